// Round 6
// baseline (1799664.258 us; speedup 1.0000x reference)
//
#include <hip/hip_runtime.h>
#include <hip/hip_bf16.h>
#include <math.h>

#define TSEQ 4096
#define EMBD 1024
#define HH   512
#define NTAGS 5
#define NGATE 2048
#define NEGV (-10000.0f)
#define START_TAG 3
#define STOP_TAG 4

typedef unsigned long long u64;
typedef unsigned int u32;

__device__ __forceinline__ float sigm(float x){ return 1.0f/(1.0f+expf(-x)); }

__device__ __forceinline__ u64 pack_pair(float h, u32 tag){
  return ((u64)tag << 32) | (u64)__float_as_uint(h);
}

// ---------------- init: prime mailbox via L3 path + zero control words ----------
// mbox layout: [dir][parity][512] u64 pairs. ctrl: [claim0, claim1, abort]
__global__ void k_init(const float* __restrict__ h0, u64* __restrict__ mbox,
                       int* __restrict__ ctrl){
  int idx = blockIdx.x*1024 + threadIdx.x;
  if (idx < 2048){
    int u   = idx & 511;
    int dp  = idx >> 9;          // 0..3
    int par = dp & 1, dir = dp >> 1;
    u64 val = par ? pack_pair(0.f, 0xFFFFFFFFu) : pack_pair(h0[dir*HH + u], 0u);
    mbox[((size_t)(dir*2 + par))*HH + u] = val;
  }
  if (idx < 3) ctrl[idx] = 0;
}

// ---------------- input projection GEMM (fp32, fused embedding gather + bias) ----
__global__ __launch_bounds__(256) void k_inproj(
    const int* __restrict__ sent, const float* __restrict__ emb,
    const float* __restrict__ Wf, const float* __restrict__ bf,
    const float* __restrict__ Wb, const float* __restrict__ bb,
    float* __restrict__ A){
  __shared__ __align__(16) float As[16][132];
  __shared__ __align__(16) float Bs[16][132];
  __shared__ int srow[128];
  const int tid = threadIdx.x;
  const int t0  = blockIdx.x * 128;
  const int ng0 = blockIdx.y * 128;
  const int dir = (ng0 >= NGATE) ? 1 : 0;
  const float* __restrict__ W    = dir ? Wb : Wf;
  const float* __restrict__ bias = dir ? bb : bf;
  const int n0 = ng0 & (NGATE - 1);
  if (tid < 128) srow[tid] = sent[t0 + tid];
  __syncthreads();
  const int lr = tid >> 2;
  const int kq = (tid & 3) * 4;
  const float* ea0 = emb + (size_t)srow[lr]      * EMBD + kq;
  const float* ea1 = emb + (size_t)srow[lr + 64] * EMBD + kq;
  const float* wb0 = W + (size_t)(n0 + lr)      * EMBD + kq;
  const float* wb1 = W + (size_t)(n0 + lr + 64) * EMBD + kq;
  const int tx = tid & 15, ty = tid >> 4;
  float acc[8][8];
  #pragma unroll
  for (int i = 0; i < 8; i++)
    #pragma unroll
    for (int j = 0; j < 8; j++) acc[i][j] = 0.f;

  for (int k0 = 0; k0 < EMBD; k0 += 16){
    float4 va0 = *(const float4*)(ea0 + k0);
    float4 va1 = *(const float4*)(ea1 + k0);
    float4 vb0 = *(const float4*)(wb0 + k0);
    float4 vb1 = *(const float4*)(wb1 + k0);
    As[kq+0][lr] = va0.x; As[kq+1][lr] = va0.y; As[kq+2][lr] = va0.z; As[kq+3][lr] = va0.w;
    As[kq+0][lr+64] = va1.x; As[kq+1][lr+64] = va1.y; As[kq+2][lr+64] = va1.z; As[kq+3][lr+64] = va1.w;
    Bs[kq+0][lr] = vb0.x; Bs[kq+1][lr] = vb0.y; Bs[kq+2][lr] = vb0.z; Bs[kq+3][lr] = vb0.w;
    Bs[kq+0][lr+64] = vb1.x; Bs[kq+1][lr+64] = vb1.y; Bs[kq+2][lr+64] = vb1.z; Bs[kq+3][lr+64] = vb1.w;
    __syncthreads();
    #pragma unroll
    for (int k = 0; k < 16; k++){
      float a[8], b[8];
      *(float4*)&a[0] = *(const float4*)&As[k][ty*8];
      *(float4*)&a[4] = *(const float4*)&As[k][ty*8 + 4];
      #pragma unroll
      for (int j = 0; j < 8; j++) b[j] = Bs[k][tx + 16*j];
      #pragma unroll
      for (int i = 0; i < 8; i++)
        #pragma unroll
        for (int j = 0; j < 8; j++)
          acc[i][j] = fmaf(a[i], b[j], acc[i][j]);
    }
    __syncthreads();
  }
  float bj[8];
  #pragma unroll
  for (int j = 0; j < 8; j++) bj[j] = bias[n0 + tx + 16*j];
  float* Abase = A + (size_t)dir * TSEQ * NGATE;
  #pragma unroll
  for (int i = 0; i < 8; i++){
    float* dst = Abase + (size_t)(t0 + ty*8 + i) * NGATE + n0 + tx;
    #pragma unroll
    for (int j = 0; j < 8; j++) dst[16*j] = acc[i][j] + bj[j];
  }
}

// ---------------- persistent BiLSTM recurrence, intra-XCD L2 exchange ----------
// 512 WGs launched; WGs self-identify their XCD via s_getreg(HW_REG_XCC_ID).
// XCD0 WGs claim the 32 forward slots, XCD1 the 32 backward slots (atomic
// claim counters); everyone else exits. All h-exchange for a direction then
// stays inside ONE XCD's L2: producers publish (tag,h) pairs with sc0 stores
// (write-through to the shared L2), consumer wave 0 polls with sc0 loads
// (L1-bypass, L2-served, ~200cyc RT vs ~2us through the L3 coherence point).
// Tag-certification + parity ping-pong + WAR causality identical to before.
__global__ __launch_bounds__(512) void k_lstm(
    const float* __restrict__ Whf, const float* __restrict__ Whb,
    const float* __restrict__ h0, const float* __restrict__ c0,
    const float* __restrict__ A, float* __restrict__ hseq,
    u64* __restrict__ mbox, int* __restrict__ ctrl){
  u32 xcc;
  asm volatile("s_getreg_b32 %0, hwreg(HW_REG_XCC_ID)" : "=s"(xcc));
  const int tid = threadIdx.x;
  __shared__ int slot_s;
  const int dir = (xcc == 0u) ? 0 : ((xcc == 1u) ? 1 : -1);
  if (tid == 0){
    int sl = 0x7FFFFFFF;
    if (dir >= 0)
      sl = __hip_atomic_fetch_add(&ctrl[dir], 1, __ATOMIC_RELAXED, __HIP_MEMORY_SCOPE_AGENT);
    slot_s = sl;
  }
  __syncthreads();
  const int wg = slot_s;
  if (dir < 0 || wg >= 32) return;

  const int lane = tid & 63;
  const int ul   = tid >> 5;        // unit local 0..15
  const int g    = (tid >> 3) & 3;  // gate i,f,g,o
  const int q    = tid & 7;         // column octant
  const int unit = wg*16 + ul;
  const float* __restrict__ Wh = dir ? Whb : Whf;

  float wreg[64];                   // Wh[g*512+unit][q*64 .. q*64+63]
  {
    const float* wr = Wh + (size_t)(g*HH + unit)*HH + q*64;
    #pragma unroll
    for (int j4 = 0; j4 < 16; j4++){
      float4 vv = *(const float4*)(wr + 4*j4);
      wreg[4*j4+0]=vv.x; wreg[4*j4+1]=vv.y; wreg[4*j4+2]=vv.z; wreg[4*j4+3]=vv.w;
    }
  }
  float creg = 0.f;
  if (g == 0 && q == 0) creg = c0[dir*HH + unit];

  __shared__ __align__(16) float hl[2][8*68];
  u64* mb = mbox + (size_t)dir*2*HH;      // [parity][512]
  const float* __restrict__ Ab = A + (size_t)dir*TSEQ*NGATE;
  int* abortf = ctrl + 2;

  // Seed parity0 (tag 0, h0) through the LOCAL L2 so sc0 pollers see it even
  // if stale lines from a previous graph replay are resident.
  if (g == 0 && q == 0){
    u64 pk0 = pack_pair(h0[dir*HH + unit], 0u);
    u64 a0 = (u64)(mb + unit);
    asm volatile("global_store_dwordx2 %0, %1, off sc0" :: "v"(a0), "v"(pk0) : "memory");
  }

  for (int s = 0; s < TSEQ; s++){
    const int t = dir ? (TSEQ - 1 - s) : s;
    float av = 0.f;
    if (q == 0) av = Ab[(size_t)t*NGATE + g*HH + unit];

    if (tid < 64){                   // wave 0: poll own direction's buffer (L2)
      u64* src = mb + (size_t)(s & 1)*HH;
      const u64 base = (u64)(src + lane);
      u64 v0,v1,v2,v3,v4,v5,v6,v7;
      int tries = 0;
      while (true){
        asm volatile(
          "global_load_dwordx2 %0, %8, off sc0\n\t"
          "global_load_dwordx2 %1, %8, off offset:512 sc0\n\t"
          "global_load_dwordx2 %2, %8, off offset:1024 sc0\n\t"
          "global_load_dwordx2 %3, %8, off offset:1536 sc0\n\t"
          "global_load_dwordx2 %4, %8, off offset:2048 sc0\n\t"
          "global_load_dwordx2 %5, %8, off offset:2560 sc0\n\t"
          "global_load_dwordx2 %6, %8, off offset:3072 sc0\n\t"
          "global_load_dwordx2 %7, %8, off offset:3584 sc0\n\t"
          "s_waitcnt vmcnt(0)"
          : "=&v"(v0),"=&v"(v1),"=&v"(v2),"=&v"(v3),
            "=&v"(v4),"=&v"(v5),"=&v"(v6),"=&v"(v7)
          : "v"(base) : "memory");
        const u32 su = (u32)s;
        int ok = ((u32)(v0>>32)==su) & ((u32)(v1>>32)==su) &
                 ((u32)(v2>>32)==su) & ((u32)(v3>>32)==su) &
                 ((u32)(v4>>32)==su) & ((u32)(v5>>32)==su) &
                 ((u32)(v6>>32)==su) & ((u32)(v7>>32)==su);
        if (__all(ok)) break;
        ++tries;
        if ((tries & 2047) == 0){    // safety net: never hang
          if (__hip_atomic_load(abortf, __ATOMIC_RELAXED, __HIP_MEMORY_SCOPE_AGENT)) break;
          if (tries > 50000){
            __hip_atomic_store(abortf, 1, __ATOMIC_RELAXED, __HIP_MEMORY_SCOPE_AGENT);
            break;
          }
        }
      }
      float* hb = hl[s & 1];
      hb[0*68 + lane] = __uint_as_float((u32)v0);
      hb[1*68 + lane] = __uint_as_float((u32)v1);
      hb[2*68 + lane] = __uint_as_float((u32)v2);
      hb[3*68 + lane] = __uint_as_float((u32)v3);
      hb[4*68 + lane] = __uint_as_float((u32)v4);
      hb[5*68 + lane] = __uint_as_float((u32)v5);
      hb[6*68 + lane] = __uint_as_float((u32)v6);
      hb[7*68 + lane] = __uint_as_float((u32)v7);
    }
    __syncthreads();

    // matvec: 64 FMAs from LDS chunk q
    const float* hq = hl[s & 1] + q*68;
    float p0 = 0.f, p1 = 0.f, p2 = 0.f, p3 = 0.f;
    #pragma unroll
    for (int j4 = 0; j4 < 16; j4++){
      float4 h4 = *(const float4*)(hq + 4*j4);
      p0 = fmaf(wreg[4*j4+0], h4.x, p0);
      p1 = fmaf(wreg[4*j4+1], h4.y, p1);
      p2 = fmaf(wreg[4*j4+2], h4.z, p2);
      p3 = fmaf(wreg[4*j4+3], h4.w, p3);
    }
    float acc = ((p0 + p1) + (p2 + p3)) + av;
    acc += __shfl_xor(acc, 1);
    acc += __shfl_xor(acc, 2);
    acc += __shfl_xor(acc, 4);
    const float act = (g == 2) ? tanhf(acc) : sigm(acc);
    const float f_ = __shfl_down(act, 8);
    const float g_ = __shfl_down(act, 16);
    const float o_ = __shfl_down(act, 24);
    if (g == 0 && q == 0){
      const float c2 = f_*creg + act*g_;
      const float h2 = o_*tanhf(c2);
      creg = c2;
      hseq[((size_t)dir*TSEQ + t)*HH + unit] = h2;
      const u64 pk = pack_pair(h2, (u32)(s + 1));
      const u64 da = (u64)(mb + (size_t)((s + 1) & 1)*HH + unit);
      asm volatile("global_store_dwordx2 %0, %1, off sc0" :: "v"(da), "v"(pk) : "memory");
    }
  }
}

// ---------------- emission features ----------------
__global__ __launch_bounds__(64) void k_feats(
    const float* __restrict__ Wout, const float* __restrict__ bout,
    const float* __restrict__ hseq, float* __restrict__ feats){
  const int t = blockIdx.x, lane = threadIdx.x;
  const float* hf = hseq + (size_t)t*HH;
  const float* hb = hseq + (size_t)(TSEQ + t)*HH;
  float x[16];
  #pragma unroll
  for (int k = 0; k < 8; k++) x[k]     = hf[lane + 64*k];
  #pragma unroll
  for (int k = 0; k < 8; k++) x[8 + k] = hb[lane + 64*k];
  #pragma unroll
  for (int n = 0; n < NTAGS; n++){
    const float* wr = Wout + (size_t)n*(2*HH);
    float p = 0.f;
    #pragma unroll
    for (int k = 0; k < 8; k++) p = fmaf(x[k],     wr[lane + 64*k],      p);
    #pragma unroll
    for (int k = 0; k < 8; k++) p = fmaf(x[8 + k], wr[HH + lane + 64*k], p);
    #pragma unroll
    for (int d = 1; d < 64; d <<= 1) p += __shfl_xor(p, d);
    if (lane == 0) feats[t*8 + n] = p + bout[n];
  }
}

// ---------------- Viterbi forward + backtrack (1 wave) ----------------
__global__ __launch_bounds__(64) void k_viterbi(
    const float* __restrict__ trans, const float* __restrict__ feats,
    int* __restrict__ bpw, float* __restrict__ out){
  const int lane = threadIdx.x;
  const int to = lane >> 3, from = lane & 7;
  const bool v_to = (to < NTAGS), v_from = (from < NTAGS);
  const float tv = (v_to && v_from) ? trans[to*NTAGS + from] : -1e30f;
  float fv = (from == START_TAG) ? 0.f : NEGV;
  __shared__ float fsh[512];
  for (int t0 = 0; t0 < TSEQ; t0 += 64){
    __syncthreads();
    #pragma unroll
    for (int i = 0; i < 8; i++) fsh[lane + 64*i] = feats[t0*8 + lane + 64*i];
    __syncthreads();
    for (int i = 0; i < 64; i++){
      const int t = t0 + i;
      float bv = fv + tv; int bi = from;
      #pragma unroll
      for (int d = 1; d < 8; d <<= 1){
        float ov = __shfl_xor(bv, d);
        int   oi = __shfl_xor(bi, d);
        if (ov > bv || (ov == bv && oi < bi)){ bv = ov; bi = oi; }
      }
      float nf = bv + fsh[i*8 + to];
      int wv = 0;
      #pragma unroll
      for (int tt = 0; tt < 5; tt++) wv |= (__shfl(bi, tt*8) & 15) << (4*tt);
      if (lane == 0) bpw[t] = wv;
      float nfv = __shfl(nf, from*8);
      fv = v_from ? nfv : NEGV;
    }
  }
  float bv = fv + (v_from ? trans[STOP_TAG*NTAGS + from] : -1e30f);
  int bi = from;
  #pragma unroll
  for (int d = 1; d < 8; d <<= 1){
    float ov = __shfl_xor(bv, d);
    int   oi = __shfl_xor(bi, d);
    if (ov > bv || (ov == bv && oi < bi)){ bv = ov; bi = oi; }
  }
  float score = __shfl(bv, 0);
  int btag = __shfl(bi, 0);
  if (lane == 0){ out[0] = score; out[TSEQ] = (float)btag; }
  int tag = btag;
  for (int b = 63; b >= 0; b--){
    int v = bpw[b*64 + lane];
    for (int i = 63; i >= 0; i--){
      int t = b*64 + i;
      if (t == 0) break;
      int wv2 = __shfl(v, i);
      int prev = (wv2 >> (tag*4)) & 15;
      if (lane == 0) out[t] = (float)prev;
      tag = prev;
    }
  }
}

extern "C" void kernel_launch(void* const* d_in, const int* in_sizes, int n_in,
                              void* d_out, int out_size, void* d_ws, size_t ws_size,
                              hipStream_t stream) {
  const int*   sent = (const int*)  d_in[0];
  const float* emb  = (const float*)d_in[1];
  const float* Wihf = (const float*)d_in[2];
  const float* Whhf = (const float*)d_in[3];
  const float* bf_  = (const float*)d_in[4];
  const float* Wihb = (const float*)d_in[5];
  const float* Whhb = (const float*)d_in[6];
  const float* bb_  = (const float*)d_in[7];
  const float* Wout = (const float*)d_in[8];
  const float* bout = (const float*)d_in[9];
  const float* trans= (const float*)d_in[10];
  const float* h0   = (const float*)d_in[11];
  const float* c0   = (const float*)d_in[12];
  float* out = (float*)d_out;

  float* ws   = (float*)d_ws;
  float* A    = ws;                                   // [2][T][2048]
  float* hseq = A    + (size_t)2*TSEQ*NGATE;          // [2][T][512]
  u64*   mbox = (u64*)(hseq + (size_t)2*TSEQ*HH);     // [2][2][512] (tag,val)
  float* fe   = (float*)(mbox + 2048);                // [T][8]
  int*   bpw  = (int*)(fe + (size_t)TSEQ*8);          // [T] packed nibbles
  int*   ctrl = bpw + TSEQ;                           // [claim0, claim1, abort]
  (void)ws_size;

  k_init<<<2, 1024, 0, stream>>>(h0, mbox, ctrl);
  dim3 gg(TSEQ/128, 4096/128);
  k_inproj<<<gg, 256, 0, stream>>>(sent, emb, Wihf, bf_, Wihb, bb_, A);
  k_lstm<<<512, 512, 0, stream>>>(Whhf, Whhb, h0, c0, A, hseq, mbox, ctrl);
  k_feats<<<TSEQ, 64, 0, stream>>>(Wout, bout, hseq, fe);
  k_viterbi<<<1, 64, 0, stream>>>(trans, fe, bpw, out);
}

// Round 7
// 10763.937 us; speedup vs baseline: 167.1939x; 167.1939x over previous
//
#include <hip/hip_runtime.h>
#include <hip/hip_bf16.h>
#include <math.h>

#define TSEQ 4096
#define EMBD 1024
#define HH   512
#define NTAGS 5
#define NGATE 2048
#define NEGV (-10000.0f)
#define START_TAG 3
#define STOP_TAG 4

typedef unsigned long long u64;
typedef unsigned int u32;

__device__ __forceinline__ float sigm(float x){ return 1.0f/(1.0f+expf(-x)); }

__device__ __forceinline__ u64 pack_pair(float h, u32 tag){
  return ((u64)tag << 32) | (u64)__float_as_uint(h);
}

// ---------------- init: prime h pair buffers (tag 0 = h0, other buffer invalid) ----
__global__ void k_init(const float* __restrict__ h0, u64* __restrict__ hx2){
  int tid = threadIdx.x;
  if (tid < 1024){
    int dir = tid >> 9, u = tid & 511;
    hx2[(dir*2 + 0)*HH + u] = pack_pair(h0[dir*HH + u], 0u);
    hx2[(dir*2 + 1)*HH + u] = pack_pair(0.f, 0xFFFFFFFFu);
  }
}

// ---------------- input projection GEMM (fp32, fused embedding gather + bias) ----
// A[dir][t][n] = sum_k W_ih[n][k] * emb[sent[t]][k] + b[n]
__global__ __launch_bounds__(256) void k_inproj(
    const int* __restrict__ sent, const float* __restrict__ emb,
    const float* __restrict__ Wf, const float* __restrict__ bf,
    const float* __restrict__ Wb, const float* __restrict__ bb,
    float* __restrict__ A){
  __shared__ __align__(16) float As[16][132];
  __shared__ __align__(16) float Bs[16][132];
  __shared__ int srow[128];
  const int tid = threadIdx.x;
  const int t0  = blockIdx.x * 128;
  const int ng0 = blockIdx.y * 128;
  const int dir = (ng0 >= NGATE) ? 1 : 0;
  const float* __restrict__ W    = dir ? Wb : Wf;
  const float* __restrict__ bias = dir ? bb : bf;
  const int n0 = ng0 & (NGATE - 1);
  if (tid < 128) srow[tid] = sent[t0 + tid];
  __syncthreads();
  const int lr = tid >> 2;          // loader row 0..63 (two passes)
  const int kq = (tid & 3) * 4;     // k sub-offset within 16
  const float* ea0 = emb + (size_t)srow[lr]      * EMBD + kq;
  const float* ea1 = emb + (size_t)srow[lr + 64] * EMBD + kq;
  const float* wb0 = W + (size_t)(n0 + lr)      * EMBD + kq;
  const float* wb1 = W + (size_t)(n0 + lr + 64) * EMBD + kq;
  const int tx = tid & 15, ty = tid >> 4;
  float acc[8][8];
  #pragma unroll
  for (int i = 0; i < 8; i++)
    #pragma unroll
    for (int j = 0; j < 8; j++) acc[i][j] = 0.f;

  for (int k0 = 0; k0 < EMBD; k0 += 16){
    float4 va0 = *(const float4*)(ea0 + k0);
    float4 va1 = *(const float4*)(ea1 + k0);
    float4 vb0 = *(const float4*)(wb0 + k0);
    float4 vb1 = *(const float4*)(wb1 + k0);
    As[kq+0][lr] = va0.x; As[kq+1][lr] = va0.y; As[kq+2][lr] = va0.z; As[kq+3][lr] = va0.w;
    As[kq+0][lr+64] = va1.x; As[kq+1][lr+64] = va1.y; As[kq+2][lr+64] = va1.z; As[kq+3][lr+64] = va1.w;
    Bs[kq+0][lr] = vb0.x; Bs[kq+1][lr] = vb0.y; Bs[kq+2][lr] = vb0.z; Bs[kq+3][lr] = vb0.w;
    Bs[kq+0][lr+64] = vb1.x; Bs[kq+1][lr+64] = vb1.y; Bs[kq+2][lr+64] = vb1.z; Bs[kq+3][lr+64] = vb1.w;
    __syncthreads();
    #pragma unroll
    for (int k = 0; k < 16; k++){
      float a[8], b[8];
      *(float4*)&a[0] = *(const float4*)&As[k][ty*8];
      *(float4*)&a[4] = *(const float4*)&As[k][ty*8 + 4];
      #pragma unroll
      for (int j = 0; j < 8; j++) b[j] = Bs[k][tx + 16*j];
      #pragma unroll
      for (int i = 0; i < 8; i++)
        #pragma unroll
        for (int j = 0; j < 8; j++)
          acc[i][j] = fmaf(a[i], b[j], acc[i][j]);
    }
    __syncthreads();
  }
  float bj[8];
  #pragma unroll
  for (int j = 0; j < 8; j++) bj[j] = bias[n0 + tx + 16*j];
  float* Abase = A + (size_t)dir * TSEQ * NGATE;
  #pragma unroll
  for (int i = 0; i < 8; i++){
    float* dst = Abase + (size_t)(t0 + ty*8 + i) * NGATE + n0 + tx;
    #pragma unroll
    for (int j = 0; j < 8; j++) dst[16*j] = acc[i][j] + bj[j];
  }
}

// ---------------- persistent BiLSTM recurrence ----------------
// 64 WGs x 512 thr: 32 WGs/dir, 16 units/WG (R3 structure, validated).
// h exchange: shared pull of self-certifying (tag,value) u64 pairs.
// NEW vs R3: two-lead proxy poll. Wave 0 polls just TWO uniform-address
// pairs (leads of WGs wg+1 / wg+17 -> <=2 readers per polled line, 2
// line-requests per round instead of 64) and only after both leads carry
// tag s does it bulk-read the 512 pairs ONCE, then masked straggler fixup.
// This removes the contended multi-round catch burst at the coherence point.
// Publish order: pair store FIRST (critical path), hseq store after.
__global__ __launch_bounds__(512) void k_lstm(
    const float* __restrict__ Whf, const float* __restrict__ Whb,
    const float* __restrict__ c0,
    const float* __restrict__ A, float* __restrict__ hseq,
    u64* __restrict__ hx2){
  const int bid  = blockIdx.x;
  const int dir  = bid >> 5;
  const int wg   = bid & 31;
  const int tid  = threadIdx.x;
  const int lane = tid & 63;
  const int ul   = tid >> 5;        // unit local 0..15
  const int g    = (tid >> 3) & 3;  // gate i,f,g,o
  const int q    = tid & 7;         // column octant
  const int unit = wg*16 + ul;
  const float* __restrict__ Wh = dir ? Whb : Whf;

  float wreg[64];                   // Wh[g*512+unit][q*64 .. q*64+63]
  {
    const float* wr = Wh + (size_t)(g*HH + unit)*HH + q*64;
    #pragma unroll
    for (int j4 = 0; j4 < 16; j4++){
      float4 vv = *(const float4*)(wr + 4*j4);
      wreg[4*j4+0]=vv.x; wreg[4*j4+1]=vv.y; wreg[4*j4+2]=vv.z; wreg[4*j4+3]=vv.w;
    }
  }
  float creg = 0.f;
  if (g == 0 && q == 0) creg = c0[dir*HH + unit];

  __shared__ __align__(16) float hl[2][8*68];   // [buf][j*68 + c], pad->bank-rotate
  u64* mb = hx2 + (size_t)dir*2*HH;
  const float* __restrict__ Ab = A + (size_t)dir*TSEQ*NGATE;
  const int lead0 = ((wg + 1)  & 31) * 16;   // another WG's first unit
  const int lead1 = ((wg + 17) & 31) * 16;

  for (int s = 0; s < TSEQ; s++){
    const int t = dir ? (TSEQ - 1 - s) : s;
    // prefetch this step's input-projection value (issued before the poll)
    float av = 0.f;
    if (q == 0) av = Ab[(size_t)t*NGATE + g*HH + unit];

    if (tid < 64){                   // wave 0: lead poll -> bulk read -> fixup
      u64* src = mb + (size_t)(s & 1)*HH;
      const u32 su = (u32)s;
      // (1) two-lead proxy poll, uniform addresses (1 transaction each)
      while (true){
        u64 l0 = __hip_atomic_load(&src[lead0], __ATOMIC_RELAXED, __HIP_MEMORY_SCOPE_AGENT);
        u64 l1 = __hip_atomic_load(&src[lead1], __ATOMIC_RELAXED, __HIP_MEMORY_SCOPE_AGENT);
        if (((u32)(l0 >> 32) == su) & ((u32)(l1 >> 32) == su)) break;
      }
      // (2) one bulk read of all 512 pairs
      u64 v[8];
      #pragma unroll
      for (int j = 0; j < 8; j++)
        v[j] = __hip_atomic_load(&src[j*64 + lane], __ATOMIC_RELAXED, __HIP_MEMORY_SCOPE_AGENT);
      // (3) masked straggler fixup (publisher skew)
      unsigned need = 0xFFu;
      while (true){
        #pragma unroll
        for (int j = 0; j < 8; j++)
          if (((need >> j) & 1u) && ((u32)(v[j] >> 32) == su)) need &= ~(1u << j);
        if (__all(need == 0u)) break;
        #pragma unroll
        for (int j = 0; j < 8; j++)
          if ((need >> j) & 1u)
            v[j] = __hip_atomic_load(&src[j*64 + lane], __ATOMIC_RELAXED, __HIP_MEMORY_SCOPE_AGENT);
      }
      float* hb = hl[s & 1];
      #pragma unroll
      for (int j = 0; j < 8; j++) hb[j*68 + lane] = __uint_as_float((u32)v[j]);
    }
    __syncthreads();

    // matvec: 64 FMAs from LDS chunk q
    const float* hq = hl[s & 1] + q*68;
    float p0 = 0.f, p1 = 0.f, p2 = 0.f, p3 = 0.f;
    #pragma unroll
    for (int j4 = 0; j4 < 16; j4++){
      float4 h4 = *(const float4*)(hq + 4*j4);
      p0 = fmaf(wreg[4*j4+0], h4.x, p0);
      p1 = fmaf(wreg[4*j4+1], h4.y, p1);
      p2 = fmaf(wreg[4*j4+2], h4.z, p2);
      p3 = fmaf(wreg[4*j4+3], h4.w, p3);
    }
    float acc = ((p0 + p1) + (p2 + p3)) + av;
    acc += __shfl_xor(acc, 1);
    acc += __shfl_xor(acc, 2);
    acc += __shfl_xor(acc, 4);
    // parallel nonlinearity: one transcendental per gate lane
    const float act = (g == 2) ? tanhf(acc) : sigm(acc);
    const float f_ = __shfl_down(act, 8);
    const float g_ = __shfl_down(act, 16);
    const float o_ = __shfl_down(act, 24);
    if (g == 0 && q == 0){
      const float c2 = f_*creg + act*g_;
      const float h2 = o_*tanhf(c2);
      creg = c2;
      // publish FIRST (critical path), bookkeeping store after
      __hip_atomic_store(&mb[(size_t)((s + 1) & 1)*HH + unit], pack_pair(h2, (u32)(s + 1)),
                         __ATOMIC_RELAXED, __HIP_MEMORY_SCOPE_AGENT);
      hseq[((size_t)dir*TSEQ + t)*HH + unit] = h2;
    }
  }
}

// ---------------- emission features: feats[t][n] = lstm_out[t] . W_out[n] + b ----
__global__ __launch_bounds__(64) void k_feats(
    const float* __restrict__ Wout, const float* __restrict__ bout,
    const float* __restrict__ hseq, float* __restrict__ feats){
  const int t = blockIdx.x, lane = threadIdx.x;
  const float* hf = hseq + (size_t)t*HH;
  const float* hb = hseq + (size_t)(TSEQ + t)*HH;
  float x[16];
  #pragma unroll
  for (int k = 0; k < 8; k++) x[k]     = hf[lane + 64*k];
  #pragma unroll
  for (int k = 0; k < 8; k++) x[8 + k] = hb[lane + 64*k];
  #pragma unroll
  for (int n = 0; n < NTAGS; n++){
    const float* wr = Wout + (size_t)n*(2*HH);
    float p = 0.f;
    #pragma unroll
    for (int k = 0; k < 8; k++) p = fmaf(x[k],     wr[lane + 64*k],      p);
    #pragma unroll
    for (int k = 0; k < 8; k++) p = fmaf(x[8 + k], wr[HH + lane + 64*k], p);
    #pragma unroll
    for (int d = 1; d < 64; d <<= 1) p += __shfl_xor(p, d);
    if (lane == 0) feats[t*8 + n] = p + bout[n];
  }
}

// ---------------- Viterbi forward + backtrack (1 wave) ----------------
// lane = to*8 + from (5x5 valid). First-max tie-break matches jnp.argmax.
__global__ __launch_bounds__(64) void k_viterbi(
    const float* __restrict__ trans, const float* __restrict__ feats,
    int* __restrict__ bpw, float* __restrict__ out){
  const int lane = threadIdx.x;
  const int to = lane >> 3, from = lane & 7;
  const bool v_to = (to < NTAGS), v_from = (from < NTAGS);
  const float tv = (v_to && v_from) ? trans[to*NTAGS + from] : -1e30f;
  float fv = (from == START_TAG) ? 0.f : NEGV;    // fv for my 'from' tag
  __shared__ float fsh[512];
  for (int t0 = 0; t0 < TSEQ; t0 += 64){
    __syncthreads();
    #pragma unroll
    for (int i = 0; i < 8; i++) fsh[lane + 64*i] = feats[t0*8 + lane + 64*i];
    __syncthreads();
    for (int i = 0; i < 64; i++){
      const int t = t0 + i;
      float bv = fv + tv; int bi = from;
      #pragma unroll
      for (int d = 1; d < 8; d <<= 1){
        float ov = __shfl_xor(bv, d);
        int   oi = __shfl_xor(bi, d);
        if (ov > bv || (ov == bv && oi < bi)){ bv = ov; bi = oi; }
      }
      float nf = bv + fsh[i*8 + to];       // new fv[to] (garbage for to>=5, discarded)
      int wv = 0;
      #pragma unroll
      for (int tt = 0; tt < 5; tt++) wv |= (__shfl(bi, tt*8) & 15) << (4*tt);
      if (lane == 0) bpw[t] = wv;
      float nfv = __shfl(nf, from*8);
      fv = v_from ? nfv : NEGV;
    }
  }
  // terminal: fv + trans[STOP][from]
  float bv = fv + (v_from ? trans[STOP_TAG*NTAGS + from] : -1e30f);
  int bi = from;
  #pragma unroll
  for (int d = 1; d < 8; d <<= 1){
    float ov = __shfl_xor(bv, d);
    int   oi = __shfl_xor(bi, d);
    if (ov > bv || (ov == bv && oi < bi)){ bv = ov; bi = oi; }
  }
  float score = __shfl(bv, 0);
  int btag = __shfl(bi, 0);
  if (lane == 0){ out[0] = score; out[TSEQ] = (float)btag; }   // out[1 + (T-1)]
  int tag = btag;
  for (int b = 63; b >= 0; b--){
    int v = bpw[b*64 + lane];
    for (int i = 63; i >= 0; i--){
      int t = b*64 + i;
      if (t == 0) break;                     // bpw[0] points at virtual START
      int wv2 = __shfl(v, i);
      int prev = (wv2 >> (tag*4)) & 15;
      if (lane == 0) out[t] = (float)prev;   // out[1 + (t-1)]
      tag = prev;
    }
  }
}

extern "C" void kernel_launch(void* const* d_in, const int* in_sizes, int n_in,
                              void* d_out, int out_size, void* d_ws, size_t ws_size,
                              hipStream_t stream) {
  const int*   sent = (const int*)  d_in[0];
  const float* emb  = (const float*)d_in[1];
  const float* Wihf = (const float*)d_in[2];
  const float* Whhf = (const float*)d_in[3];
  const float* bf_  = (const float*)d_in[4];
  const float* Wihb = (const float*)d_in[5];
  const float* Whhb = (const float*)d_in[6];
  const float* bb_  = (const float*)d_in[7];
  const float* Wout = (const float*)d_in[8];
  const float* bout = (const float*)d_in[9];
  const float* trans= (const float*)d_in[10];
  const float* h0   = (const float*)d_in[11];
  const float* c0   = (const float*)d_in[12];
  float* out = (float*)d_out;

  float* ws   = (float*)d_ws;
  float* A    = ws;                                  // [2][T][2048]
  float* hseq = A    + (size_t)2*TSEQ*NGATE;         // [2][T][512]
  u64*   hx2  = (u64*)(hseq + (size_t)2*TSEQ*HH);    // [2][2][512] (tag,val) pairs
  float* fe   = (float*)(hx2 + 2048);                // [T][8]
  int*   bpw  = (int*)(fe + (size_t)TSEQ*8);         // [T] packed nibbles
  (void)ws_size;

  k_init<<<1, 1024, 0, stream>>>(h0, hx2);
  dim3 gg(TSEQ/128, 4096/128);
  k_inproj<<<gg, 256, 0, stream>>>(sent, emb, Wihf, bf_, Wihb, bb_, A);
  k_lstm<<<64, 512, 0, stream>>>(Whhf, Whhb, c0, A, hseq, hx2);
  k_feats<<<TSEQ, 64, 0, stream>>>(Wout, bout, hseq, fe);
  k_viterbi<<<1, 64, 0, stream>>>(trans, fe, bpw, out);
}

// Round 8
// 10302.002 us; speedup vs baseline: 174.6907x; 1.0448x over previous
//
#include <hip/hip_runtime.h>
#include <hip/hip_bf16.h>
#include <math.h>

#define TSEQ 4096
#define EMBD 1024
#define HH   512
#define NTAGS 5
#define NGATE 2048
#define NEGV (-10000.0f)
#define START_TAG 3
#define STOP_TAG 4

typedef unsigned long long u64;
typedef unsigned int u32;

__device__ __forceinline__ float sigm(float x){ return 1.0f/(1.0f+expf(-x)); }

__device__ __forceinline__ u64 pack_pair(float h, u32 tag){
  return ((u64)tag << 32) | (u64)__float_as_uint(h);
}

// ---------------- init: prime h pair buffers (tag 0 = h0, other buffer invalid) ----
__global__ void k_init(const float* __restrict__ h0, u64* __restrict__ hx2){
  int tid = threadIdx.x;
  if (tid < 1024){
    int dir = tid >> 9, u = tid & 511;
    hx2[(dir*2 + 0)*HH + u] = pack_pair(h0[dir*HH + u], 0u);
    hx2[(dir*2 + 1)*HH + u] = pack_pair(0.f, 0xFFFFFFFFu);
  }
}

// ---------------- input projection GEMM (fp32, fused embedding gather + bias) ----
// A[dir][t][n] = sum_k W_ih[n][k] * emb[sent[t]][k] + b[n]
__global__ __launch_bounds__(256) void k_inproj(
    const int* __restrict__ sent, const float* __restrict__ emb,
    const float* __restrict__ Wf, const float* __restrict__ bf,
    const float* __restrict__ Wb, const float* __restrict__ bb,
    float* __restrict__ A){
  __shared__ __align__(16) float As[16][132];
  __shared__ __align__(16) float Bs[16][132];
  __shared__ int srow[128];
  const int tid = threadIdx.x;
  const int t0  = blockIdx.x * 128;
  const int ng0 = blockIdx.y * 128;
  const int dir = (ng0 >= NGATE) ? 1 : 0;
  const float* __restrict__ W    = dir ? Wb : Wf;
  const float* __restrict__ bias = dir ? bb : bf;
  const int n0 = ng0 & (NGATE - 1);
  if (tid < 128) srow[tid] = sent[t0 + tid];
  __syncthreads();
  const int lr = tid >> 2;          // loader row 0..63 (two passes)
  const int kq = (tid & 3) * 4;     // k sub-offset within 16
  const float* ea0 = emb + (size_t)srow[lr]      * EMBD + kq;
  const float* ea1 = emb + (size_t)srow[lr + 64] * EMBD + kq;
  const float* wb0 = W + (size_t)(n0 + lr)      * EMBD + kq;
  const float* wb1 = W + (size_t)(n0 + lr + 64) * EMBD + kq;
  const int tx = tid & 15, ty = tid >> 4;
  float acc[8][8];
  #pragma unroll
  for (int i = 0; i < 8; i++)
    #pragma unroll
    for (int j = 0; j < 8; j++) acc[i][j] = 0.f;

  for (int k0 = 0; k0 < EMBD; k0 += 16){
    float4 va0 = *(const float4*)(ea0 + k0);
    float4 va1 = *(const float4*)(ea1 + k0);
    float4 vb0 = *(const float4*)(wb0 + k0);
    float4 vb1 = *(const float4*)(wb1 + k0);
    As[kq+0][lr] = va0.x; As[kq+1][lr] = va0.y; As[kq+2][lr] = va0.z; As[kq+3][lr] = va0.w;
    As[kq+0][lr+64] = va1.x; As[kq+1][lr+64] = va1.y; As[kq+2][lr+64] = va1.z; As[kq+3][lr+64] = va1.w;
    Bs[kq+0][lr] = vb0.x; Bs[kq+1][lr] = vb0.y; Bs[kq+2][lr] = vb0.z; Bs[kq+3][lr] = vb0.w;
    Bs[kq+0][lr+64] = vb1.x; Bs[kq+1][lr+64] = vb1.y; Bs[kq+2][lr+64] = vb1.z; Bs[kq+3][lr+64] = vb1.w;
    __syncthreads();
    #pragma unroll
    for (int k = 0; k < 16; k++){
      float a[8], b[8];
      *(float4*)&a[0] = *(const float4*)&As[k][ty*8];
      *(float4*)&a[4] = *(const float4*)&As[k][ty*8 + 4];
      #pragma unroll
      for (int j = 0; j < 8; j++) b[j] = Bs[k][tx + 16*j];
      #pragma unroll
      for (int i = 0; i < 8; i++)
        #pragma unroll
        for (int j = 0; j < 8; j++)
          acc[i][j] = fmaf(a[i], b[j], acc[i][j]);
    }
    __syncthreads();
  }
  float bj[8];
  #pragma unroll
  for (int j = 0; j < 8; j++) bj[j] = bias[n0 + tx + 16*j];
  float* Abase = A + (size_t)dir * TSEQ * NGATE;
  #pragma unroll
  for (int i = 0; i < 8; i++){
    float* dst = Abase + (size_t)(t0 + ty*8 + i) * NGATE + n0 + tx;
    #pragma unroll
    for (int j = 0; j < 8; j++) dst[16*j] = acc[i][j] + bj[j];
  }
}

// ---------------- persistent BiLSTM recurrence ----------------
// 64 WGs x 512 thr: 32 WGs/dir, 16 units/WG. Thread map: ul = tid>>5 (unit),
// g = (tid>>3)&3 (gate), q = tid&7 (col octant).
// h exchange: shared pull of self-certifying (tag,value) u64 pairs.
// R8: DISTRIBUTED SLICE POLL — each of the 8 waves polls its own 64-pair
// slice (ONE 8B load/lane/round, masked reload of stale lanes), stages its
// slice to LDS on catch, one barrier. Merges catch+read into a single
// coherence round trip and overlaps the 8 slices (vs wave-0-only + bulk leg).
// WAR causality: each wave's publish is data-dependent on the barrier, which
// requires all slices staged -> publishing tag s+1 certifies step-s reads done.
__global__ __launch_bounds__(512) void k_lstm(
    const float* __restrict__ Whf, const float* __restrict__ Whb,
    const float* __restrict__ c0,
    const float* __restrict__ A, float* __restrict__ hseq,
    u64* __restrict__ hx2){
  const int bid  = blockIdx.x;
  const int dir  = bid >> 5;
  const int wg   = bid & 31;
  const int tid  = threadIdx.x;
  const int lane = tid & 63;
  const int wv   = tid >> 6;        // wave 0..7 = slice index
  const int ul   = tid >> 5;        // unit local 0..15
  const int g    = (tid >> 3) & 3;  // gate i,f,g,o
  const int q    = tid & 7;         // column octant
  const int unit = wg*16 + ul;
  const float* __restrict__ Wh = dir ? Whb : Whf;

  float wreg[64];                   // Wh[g*512+unit][q*64 .. q*64+63]
  {
    const float* wr = Wh + (size_t)(g*HH + unit)*HH + q*64;
    #pragma unroll
    for (int j4 = 0; j4 < 16; j4++){
      float4 vv = *(const float4*)(wr + 4*j4);
      wreg[4*j4+0]=vv.x; wreg[4*j4+1]=vv.y; wreg[4*j4+2]=vv.z; wreg[4*j4+3]=vv.w;
    }
  }
  float creg = 0.f;
  if (g == 0 && q == 0) creg = c0[dir*HH + unit];

  __shared__ __align__(16) float hl[2][8*68];   // [buf][slice*68 + lane]
  u64* mb = hx2 + (size_t)dir*2*HH;
  const float* __restrict__ Ab = A + (size_t)dir*TSEQ*NGATE;
  const int sidx = (wv << 6) + lane;            // this wave's pair index

  for (int s = 0; s < TSEQ; s++){
    const int t = dir ? (TSEQ - 1 - s) : s;
    // prefetch this step's input-projection value (independent load)
    float av = 0.f;
    if (q == 0) av = Ab[(size_t)t*NGATE + g*HH + unit];

    {  // every wave: poll own 64-pair slice (1 load/lane/round, masked reload)
      u64* src = mb + (size_t)(s & 1)*HH;
      const u32 su = (u32)s;
      u64 v = __hip_atomic_load(&src[sidx], __ATOMIC_RELAXED, __HIP_MEMORY_SCOPE_AGENT);
      while (!__all((u32)(v >> 32) == su)){
        if ((u32)(v >> 32) != su)
          v = __hip_atomic_load(&src[sidx], __ATOMIC_RELAXED, __HIP_MEMORY_SCOPE_AGENT);
      }
      hl[s & 1][wv*68 + lane] = __uint_as_float((u32)v);
    }
    __syncthreads();

    // matvec: 64 FMAs from LDS chunk q
    const float* hq = hl[s & 1] + q*68;
    float p0 = 0.f, p1 = 0.f, p2 = 0.f, p3 = 0.f;
    #pragma unroll
    for (int j4 = 0; j4 < 16; j4++){
      float4 h4 = *(const float4*)(hq + 4*j4);
      p0 = fmaf(wreg[4*j4+0], h4.x, p0);
      p1 = fmaf(wreg[4*j4+1], h4.y, p1);
      p2 = fmaf(wreg[4*j4+2], h4.z, p2);
      p3 = fmaf(wreg[4*j4+3], h4.w, p3);
    }
    float acc = ((p0 + p1) + (p2 + p3)) + av;
    acc += __shfl_xor(acc, 1);
    acc += __shfl_xor(acc, 2);
    acc += __shfl_xor(acc, 4);
    // parallel nonlinearity: one transcendental per gate lane
    const float act = (g == 2) ? tanhf(acc) : sigm(acc);
    const float f_ = __shfl_down(act, 8);
    const float g_ = __shfl_down(act, 16);
    const float o_ = __shfl_down(act, 24);
    if (g == 0 && q == 0){
      const float c2 = f_*creg + act*g_;
      const float h2 = o_*tanhf(c2);
      creg = c2;
      // publish FIRST (critical path), bookkeeping store after
      __hip_atomic_store(&mb[(size_t)((s + 1) & 1)*HH + unit], pack_pair(h2, (u32)(s + 1)),
                         __ATOMIC_RELAXED, __HIP_MEMORY_SCOPE_AGENT);
      hseq[((size_t)dir*TSEQ + t)*HH + unit] = h2;
    }
  }
}

// ---------------- emission features: feats[t][n] = lstm_out[t] . W_out[n] + b ----
__global__ __launch_bounds__(64) void k_feats(
    const float* __restrict__ Wout, const float* __restrict__ bout,
    const float* __restrict__ hseq, float* __restrict__ feats){
  const int t = blockIdx.x, lane = threadIdx.x;
  const float* hf = hseq + (size_t)t*HH;
  const float* hb = hseq + (size_t)(TSEQ + t)*HH;
  float x[16];
  #pragma unroll
  for (int k = 0; k < 8; k++) x[k]     = hf[lane + 64*k];
  #pragma unroll
  for (int k = 0; k < 8; k++) x[8 + k] = hb[lane + 64*k];
  #pragma unroll
  for (int n = 0; n < NTAGS; n++){
    const float* wr = Wout + (size_t)n*(2*HH);
    float p = 0.f;
    #pragma unroll
    for (int k = 0; k < 8; k++) p = fmaf(x[k],     wr[lane + 64*k],      p);
    #pragma unroll
    for (int k = 0; k < 8; k++) p = fmaf(x[8 + k], wr[HH + lane + 64*k], p);
    #pragma unroll
    for (int d = 1; d < 64; d <<= 1) p += __shfl_xor(p, d);
    if (lane == 0) feats[t*8 + n] = p + bout[n];
  }
}

// ---------------- Viterbi forward + backtrack (1 wave) ----------------
// lane = to*8 + from (5x5 valid). First-max tie-break matches jnp.argmax.
__global__ __launch_bounds__(64) void k_viterbi(
    const float* __restrict__ trans, const float* __restrict__ feats,
    int* __restrict__ bpw, float* __restrict__ out){
  const int lane = threadIdx.x;
  const int to = lane >> 3, from = lane & 7;
  const bool v_to = (to < NTAGS), v_from = (from < NTAGS);
  const float tv = (v_to && v_from) ? trans[to*NTAGS + from] : -1e30f;
  float fv = (from == START_TAG) ? 0.f : NEGV;    // fv for my 'from' tag
  __shared__ float fsh[512];
  for (int t0 = 0; t0 < TSEQ; t0 += 64){
    __syncthreads();
    #pragma unroll
    for (int i = 0; i < 8; i++) fsh[lane + 64*i] = feats[t0*8 + lane + 64*i];
    __syncthreads();
    for (int i = 0; i < 64; i++){
      const int t = t0 + i;
      float bv = fv + tv; int bi = from;
      #pragma unroll
      for (int d = 1; d < 8; d <<= 1){
        float ov = __shfl_xor(bv, d);
        int   oi = __shfl_xor(bi, d);
        if (ov > bv || (ov == bv && oi < bi)){ bv = ov; bi = oi; }
      }
      float nf = bv + fsh[i*8 + to];       // new fv[to] (garbage for to>=5, discarded)
      int wv = 0;
      #pragma unroll
      for (int tt = 0; tt < 5; tt++) wv |= (__shfl(bi, tt*8) & 15) << (4*tt);
      if (lane == 0) bpw[t] = wv;
      float nfv = __shfl(nf, from*8);
      fv = v_from ? nfv : NEGV;
    }
  }
  // terminal: fv + trans[STOP][from]
  float bv = fv + (v_from ? trans[STOP_TAG*NTAGS + from] : -1e30f);
  int bi = from;
  #pragma unroll
  for (int d = 1; d < 8; d <<= 1){
    float ov = __shfl_xor(bv, d);
    int   oi = __shfl_xor(bi, d);
    if (ov > bv || (ov == bv && oi < bi)){ bv = ov; bi = oi; }
  }
  float score = __shfl(bv, 0);
  int btag = __shfl(bi, 0);
  if (lane == 0){ out[0] = score; out[TSEQ] = (float)btag; }   // out[1 + (T-1)]
  int tag = btag;
  for (int b = 63; b >= 0; b--){
    int v = bpw[b*64 + lane];
    for (int i = 63; i >= 0; i--){
      int t = b*64 + i;
      if (t == 0) break;                     // bpw[0] points at virtual START
      int wv2 = __shfl(v, i);
      int prev = (wv2 >> (tag*4)) & 15;
      if (lane == 0) out[t] = (float)prev;   // out[1 + (t-1)]
      tag = prev;
    }
  }
}

extern "C" void kernel_launch(void* const* d_in, const int* in_sizes, int n_in,
                              void* d_out, int out_size, void* d_ws, size_t ws_size,
                              hipStream_t stream) {
  const int*   sent = (const int*)  d_in[0];
  const float* emb  = (const float*)d_in[1];
  const float* Wihf = (const float*)d_in[2];
  const float* Whhf = (const float*)d_in[3];
  const float* bf_  = (const float*)d_in[4];
  const float* Wihb = (const float*)d_in[5];
  const float* Whhb = (const float*)d_in[6];
  const float* bb_  = (const float*)d_in[7];
  const float* Wout = (const float*)d_in[8];
  const float* bout = (const float*)d_in[9];
  const float* trans= (const float*)d_in[10];
  const float* h0   = (const float*)d_in[11];
  const float* c0   = (const float*)d_in[12];
  float* out = (float*)d_out;

  float* ws   = (float*)d_ws;
  float* A    = ws;                                  // [2][T][2048]
  float* hseq = A    + (size_t)2*TSEQ*NGATE;         // [2][T][512]
  u64*   hx2  = (u64*)(hseq + (size_t)2*TSEQ*HH);    // [2][2][512] (tag,val) pairs
  float* fe   = (float*)(hx2 + 2048);                // [T][8]
  int*   bpw  = (int*)(fe + (size_t)TSEQ*8);         // [T] packed nibbles
  (void)ws_size;

  k_init<<<1, 1024, 0, stream>>>(h0, hx2);
  dim3 gg(TSEQ/128, 4096/128);
  k_inproj<<<gg, 256, 0, stream>>>(sent, emb, Wihf, bf_, Wihb, bb_, A);
  k_lstm<<<64, 512, 0, stream>>>(Whhf, Whhb, c0, A, hseq, hx2);
  k_feats<<<TSEQ, 64, 0, stream>>>(Wout, bout, hseq, fe);
  k_viterbi<<<1, 64, 0, stream>>>(trans, fe, bpw, out);
}

// Round 9
// 9938.578 us; speedup vs baseline: 181.0786x; 1.0366x over previous
//
#include <hip/hip_runtime.h>
#include <hip/hip_bf16.h>
#include <math.h>

#define TSEQ 4096
#define EMBD 1024
#define HH   512
#define NTAGS 5
#define NGATE 2048
#define NEGV (-10000.0f)
#define START_TAG 3
#define STOP_TAG 4
#define LSTM_WGS 64
#define PROJ_WGS 1024

typedef unsigned long long u64;
typedef unsigned int u32;

__device__ __forceinline__ float sigm(float x){ return 1.0f/(1.0f+expf(-x)); }

__device__ __forceinline__ u64 pack_pair(float h, u32 tag){
  return ((u64)tag << 32) | (u64)__float_as_uint(h);
}

// ---------------- init: prime h pair buffers + zero tile-ready counters ----------
__global__ void k_init(const float* __restrict__ h0, u64* __restrict__ hx2,
                       int* __restrict__ rdy){
  int tid = threadIdx.x;
  if (tid < 1024){
    int dir = tid >> 9, u = tid & 511;
    hx2[(dir*2 + 0)*HH + u] = pack_pair(h0[dir*HH + u], 0u);
    hx2[(dir*2 + 1)*HH + u] = pack_pair(0.f, 0xFFFFFFFFu);
  }
  if (tid < 64) rdy[tid] = 0;
}

// ---------------- fused persistent BiLSTM + input-projection GEMM ----------------
// blocks 0..63: lstm role (R8 structure, validated). blocks 64..1087: inproj
// GEMM role (512-thread variant, same per-output FMA order -> bit-identical A).
// Overlap: lstm runs on 64 CUs while GEMM blocks fill the remaining ~192 CUs.
// Sync: per-(dir,t_tile) ready counters. GEMM block: stores -> __syncthreads
// (drains all waves' stores) -> tid0 RELEASE fetch_add (wbl2 publishes the
// whole local L2, covering all waves). lstm: ACQUIRE poll once per 128 steps
// (uniform address; acquire invalidate kills any stale prefetched A lines).
// Two-ended tile production matches each direction's consumption order.
__global__ __launch_bounds__(512) void k_fused(
    const int* __restrict__ sent, const float* __restrict__ emb,
    const float* __restrict__ Wif, const float* __restrict__ bf,
    const float* __restrict__ Wib, const float* __restrict__ bb,
    const float* __restrict__ Whf, const float* __restrict__ Whb,
    const float* __restrict__ c0,
    float* __restrict__ A, float* __restrict__ hseq,
    u64* __restrict__ hx2, int* __restrict__ rdy){
  __shared__ __align__(16) char smem[17408];
  const int tid = threadIdx.x;

  if (blockIdx.x >= LSTM_WGS){
    // ================= inproj GEMM role =================
    float (*As)[132] = (float(*)[132])smem;              // 16 x 132
    float (*Bs)[132] = (float(*)[132])(smem + 8448);     // 16 x 132
    int* srow        = (int*)(smem + 16896);             // 128
    const int p   = blockIdx.x - LSTM_WGS;               // 0..1023
    const int ti  = p >> 5;                              // 0..31
    const int yy  = p & 31;                              // 0..31
    const int dir = yy >> 4;
    const int t_tile = dir ? (31 - ti) : ti;             // two-ended production
    const int t0  = t_tile * 128;
    const int n0  = (yy & 15) * 128;
    const float* __restrict__ W    = dir ? Wib : Wif;
    const float* __restrict__ bias = dir ? bb : bf;
    if (tid < 128) srow[tid] = sent[t0 + tid];
    __syncthreads();
    const int lr = tid >> 2;            // 0..127
    const int kq = (tid & 3) * 4;
    const float* ea = emb + (size_t)srow[lr]   * EMBD + kq;
    const float* wb = W + (size_t)(n0 + lr)    * EMBD + kq;
    const int tx = tid & 15, ty = tid >> 4;   // ty 0..31
    float acc[4][8];
    #pragma unroll
    for (int i = 0; i < 4; i++)
      #pragma unroll
      for (int j = 0; j < 8; j++) acc[i][j] = 0.f;

    for (int k0 = 0; k0 < EMBD; k0 += 16){
      float4 va = *(const float4*)(ea + k0);
      float4 vb = *(const float4*)(wb + k0);
      As[kq+0][lr] = va.x; As[kq+1][lr] = va.y; As[kq+2][lr] = va.z; As[kq+3][lr] = va.w;
      Bs[kq+0][lr] = vb.x; Bs[kq+1][lr] = vb.y; Bs[kq+2][lr] = vb.z; Bs[kq+3][lr] = vb.w;
      __syncthreads();
      #pragma unroll
      for (int k = 0; k < 16; k++){
        float a[4], b[8];
        *(float4*)&a[0] = *(const float4*)&As[k][ty*4];
        #pragma unroll
        for (int j = 0; j < 8; j++) b[j] = Bs[k][tx + 16*j];
        #pragma unroll
        for (int i = 0; i < 4; i++)
          #pragma unroll
          for (int j = 0; j < 8; j++)
            acc[i][j] = fmaf(a[i], b[j], acc[i][j]);
      }
      __syncthreads();
    }
    float bj[8];
    #pragma unroll
    for (int j = 0; j < 8; j++) bj[j] = bias[n0 + tx + 16*j];
    float* Abase = A + (size_t)dir * TSEQ * NGATE;
    #pragma unroll
    for (int i = 0; i < 4; i++){
      float* dst = Abase + (size_t)(t0 + ty*4 + i) * NGATE + n0 + tx;
      #pragma unroll
      for (int j = 0; j < 8; j++) dst[16*j] = acc[i][j] + bj[j];
    }
    __syncthreads();   // drains every wave's stores (HIP barrier semantics)
    if (tid == 0)
      __hip_atomic_fetch_add(&rdy[dir*32 + t_tile], 1,
                             __ATOMIC_RELEASE, __HIP_MEMORY_SCOPE_AGENT);
    return;
  }

  // ================= persistent lstm role (R8, validated) =================
  float* hlbuf = (float*)smem;                 // [2][8*68]
  const int bid  = blockIdx.x;
  const int dir  = bid >> 5;
  const int wg   = bid & 31;
  const int lane = tid & 63;
  const int wv   = tid >> 6;        // wave 0..7 = slice index
  const int ul   = tid >> 5;        // unit local 0..15
  const int g    = (tid >> 3) & 3;  // gate i,f,g,o
  const int q    = tid & 7;         // column octant
  const int unit = wg*16 + ul;
  const float* __restrict__ Wh = dir ? Whb : Whf;

  float wreg[64];                   // Wh[g*512+unit][q*64 .. q*64+63]
  {
    const float* wr = Wh + (size_t)(g*HH + unit)*HH + q*64;
    #pragma unroll
    for (int j4 = 0; j4 < 16; j4++){
      float4 vv = *(const float4*)(wr + 4*j4);
      wreg[4*j4+0]=vv.x; wreg[4*j4+1]=vv.y; wreg[4*j4+2]=vv.z; wreg[4*j4+3]=vv.w;
    }
  }
  float creg = 0.f;
  if (g == 0 && q == 0) creg = c0[dir*HH + unit];

  u64* mb = hx2 + (size_t)dir*2*HH;
  const float* __restrict__ Ab = A + (size_t)dir*TSEQ*NGATE;
  const int sidx = (wv << 6) + lane;            // this wave's pair index
  int cur_tile = -1;

  for (int s = 0; s < TSEQ; s++){
    const int t = dir ? (TSEQ - 1 - s) : s;
    // gate on this tile's input-projection readiness (once per 128 steps)
    const int tile = t >> 7;
    if (tile != cur_tile){
      cur_tile = tile;
      const int* rf = rdy + dir*32 + tile;
      while (__hip_atomic_load(rf, __ATOMIC_ACQUIRE, __HIP_MEMORY_SCOPE_AGENT) < 16)
        __builtin_amdgcn_s_sleep(2);
    }
    // prefetch this step's input-projection value (independent load)
    float av = 0.f;
    if (q == 0) av = Ab[(size_t)t*NGATE + g*HH + unit];

    {  // every wave: poll own 64-pair slice (1 load/lane/round, masked reload)
      u64* src = mb + (size_t)(s & 1)*HH;
      const u32 su = (u32)s;
      u64 v = __hip_atomic_load(&src[sidx], __ATOMIC_RELAXED, __HIP_MEMORY_SCOPE_AGENT);
      while (!__all((u32)(v >> 32) == su)){
        if ((u32)(v >> 32) != su)
          v = __hip_atomic_load(&src[sidx], __ATOMIC_RELAXED, __HIP_MEMORY_SCOPE_AGENT);
      }
      hlbuf[(s & 1)*(8*68) + wv*68 + lane] = __uint_as_float((u32)v);
    }
    __syncthreads();

    // matvec: 64 FMAs from LDS chunk q
    const float* hq = hlbuf + (s & 1)*(8*68) + q*68;
    float p0 = 0.f, p1 = 0.f, p2 = 0.f, p3 = 0.f;
    #pragma unroll
    for (int j4 = 0; j4 < 16; j4++){
      float4 h4 = *(const float4*)(hq + 4*j4);
      p0 = fmaf(wreg[4*j4+0], h4.x, p0);
      p1 = fmaf(wreg[4*j4+1], h4.y, p1);
      p2 = fmaf(wreg[4*j4+2], h4.z, p2);
      p3 = fmaf(wreg[4*j4+3], h4.w, p3);
    }
    float acc = ((p0 + p1) + (p2 + p3)) + av;
    acc += __shfl_xor(acc, 1);
    acc += __shfl_xor(acc, 2);
    acc += __shfl_xor(acc, 4);
    // parallel nonlinearity: one transcendental per gate lane
    const float act = (g == 2) ? tanhf(acc) : sigm(acc);
    const float f_ = __shfl_down(act, 8);
    const float g_ = __shfl_down(act, 16);
    const float o_ = __shfl_down(act, 24);
    if (g == 0 && q == 0){
      const float c2 = f_*creg + act*g_;
      const float h2 = o_*tanhf(c2);
      creg = c2;
      // publish FIRST (critical path), bookkeeping store after
      __hip_atomic_store(&mb[(size_t)((s + 1) & 1)*HH + unit], pack_pair(h2, (u32)(s + 1)),
                         __ATOMIC_RELAXED, __HIP_MEMORY_SCOPE_AGENT);
      hseq[((size_t)dir*TSEQ + t)*HH + unit] = h2;
    }
  }
}

// ---------------- emission features: feats[t][n] = lstm_out[t] . W_out[n] + b ----
__global__ __launch_bounds__(64) void k_feats(
    const float* __restrict__ Wout, const float* __restrict__ bout,
    const float* __restrict__ hseq, float* __restrict__ feats){
  const int t = blockIdx.x, lane = threadIdx.x;
  const float* hf = hseq + (size_t)t*HH;
  const float* hb = hseq + (size_t)(TSEQ + t)*HH;
  float x[16];
  #pragma unroll
  for (int k = 0; k < 8; k++) x[k]     = hf[lane + 64*k];
  #pragma unroll
  for (int k = 0; k < 8; k++) x[8 + k] = hb[lane + 64*k];
  #pragma unroll
  for (int n = 0; n < NTAGS; n++){
    const float* wr = Wout + (size_t)n*(2*HH);
    float p = 0.f;
    #pragma unroll
    for (int k = 0; k < 8; k++) p = fmaf(x[k],     wr[lane + 64*k],      p);
    #pragma unroll
    for (int k = 0; k < 8; k++) p = fmaf(x[8 + k], wr[HH + lane + 64*k], p);
    #pragma unroll
    for (int d = 1; d < 64; d <<= 1) p += __shfl_xor(p, d);
    if (lane == 0) feats[t*8 + n] = p + bout[n];
  }
}

// ---------------- Viterbi forward + backtrack (1 wave) ----------------
// lane = to*8 + from (5x5 valid). First-max tie-break matches jnp.argmax.
__global__ __launch_bounds__(64) void k_viterbi(
    const float* __restrict__ trans, const float* __restrict__ feats,
    int* __restrict__ bpw, float* __restrict__ out){
  const int lane = threadIdx.x;
  const int to = lane >> 3, from = lane & 7;
  const bool v_to = (to < NTAGS), v_from = (from < NTAGS);
  const float tv = (v_to && v_from) ? trans[to*NTAGS + from] : -1e30f;
  float fv = (from == START_TAG) ? 0.f : NEGV;    // fv for my 'from' tag
  __shared__ float fsh[512];
  for (int t0 = 0; t0 < TSEQ; t0 += 64){
    __syncthreads();
    #pragma unroll
    for (int i = 0; i < 8; i++) fsh[lane + 64*i] = feats[t0*8 + lane + 64*i];
    __syncthreads();
    for (int i = 0; i < 64; i++){
      const int t = t0 + i;
      float bv = fv + tv; int bi = from;
      #pragma unroll
      for (int d = 1; d < 8; d <<= 1){
        float ov = __shfl_xor(bv, d);
        int   oi = __shfl_xor(bi, d);
        if (ov > bv || (ov == bv && oi < bi)){ bv = ov; bi = oi; }
      }
      float nf = bv + fsh[i*8 + to];       // new fv[to] (garbage for to>=5, discarded)
      int wv = 0;
      #pragma unroll
      for (int tt = 0; tt < 5; tt++) wv |= (__shfl(bi, tt*8) & 15) << (4*tt);
      if (lane == 0) bpw[t] = wv;
      float nfv = __shfl(nf, from*8);
      fv = v_from ? nfv : NEGV;
    }
  }
  // terminal: fv + trans[STOP][from]
  float bv = fv + (v_from ? trans[STOP_TAG*NTAGS + from] : -1e30f);
  int bi = from;
  #pragma unroll
  for (int d = 1; d < 8; d <<= 1){
    float ov = __shfl_xor(bv, d);
    int   oi = __shfl_xor(bi, d);
    if (ov > bv || (ov == bv && oi < bi)){ bv = ov; bi = oi; }
  }
  float score = __shfl(bv, 0);
  int btag = __shfl(bi, 0);
  if (lane == 0){ out[0] = score; out[TSEQ] = (float)btag; }   // out[1 + (T-1)]
  int tag = btag;
  for (int b = 63; b >= 0; b--){
    int v = bpw[b*64 + lane];
    for (int i = 63; i >= 0; i--){
      int t = b*64 + i;
      if (t == 0) break;                     // bpw[0] points at virtual START
      int wv2 = __shfl(v, i);
      int prev = (wv2 >> (tag*4)) & 15;
      if (lane == 0) out[t] = (float)prev;   // out[1 + (t-1)]
      tag = prev;
    }
  }
}

extern "C" void kernel_launch(void* const* d_in, const int* in_sizes, int n_in,
                              void* d_out, int out_size, void* d_ws, size_t ws_size,
                              hipStream_t stream) {
  const int*   sent = (const int*)  d_in[0];
  const float* emb  = (const float*)d_in[1];
  const float* Wihf = (const float*)d_in[2];
  const float* Whhf = (const float*)d_in[3];
  const float* bf_  = (const float*)d_in[4];
  const float* Wihb = (const float*)d_in[5];
  const float* Whhb = (const float*)d_in[6];
  const float* bb_  = (const float*)d_in[7];
  const float* Wout = (const float*)d_in[8];
  const float* bout = (const float*)d_in[9];
  const float* trans= (const float*)d_in[10];
  const float* h0   = (const float*)d_in[11];
  const float* c0   = (const float*)d_in[12];
  float* out = (float*)d_out;

  float* ws   = (float*)d_ws;
  float* A    = ws;                                  // [2][T][2048]
  float* hseq = A    + (size_t)2*TSEQ*NGATE;         // [2][T][512]
  u64*   hx2  = (u64*)(hseq + (size_t)2*TSEQ*HH);    // [2][2][512] (tag,val) pairs
  float* fe   = (float*)(hx2 + 2048);                // [T][8]
  int*   bpw  = (int*)(fe + (size_t)TSEQ*8);         // [T] packed nibbles
  int*   rdy  = bpw + TSEQ;                          // [2][32] tile-ready counters
  (void)ws_size;

  k_init<<<1, 1024, 0, stream>>>(h0, hx2, rdy);
  k_fused<<<LSTM_WGS + PROJ_WGS, 512, 0, stream>>>(
      sent, emb, Wihf, bf_, Wihb, bb_, Whhf, Whhb, c0, A, hseq, hx2, rdy);
  k_feats<<<TSEQ, 64, 0, stream>>>(Wout, bout, hseq, fe);
  k_viterbi<<<1, 64, 0, stream>>>(trans, fe, bpw, out);
}

// Round 10
// 9930.291 us; speedup vs baseline: 181.2298x; 1.0008x over previous
//
#include <hip/hip_runtime.h>
#include <hip/hip_bf16.h>
#include <math.h>

#define TSEQ 4096
#define EMBD 1024
#define HH   512
#define NTAGS 5
#define NGATE 2048
#define NEGV (-10000.0f)
#define START_TAG 3
#define STOP_TAG 4
#define LSTM_WGS 64
#define PROJ_WGS 1024

typedef unsigned long long u64;
typedef unsigned int u32;

__device__ __forceinline__ float sigm(float x){ return 1.0f/(1.0f+expf(-x)); }

__device__ __forceinline__ u64 pack_pair(float h, u32 tag){
  return ((u64)tag << 32) | (u64)__float_as_uint(h);
}

// ---------------- init: prime h pair buffers + zero tile-ready counters ----------
__global__ void k_init(const float* __restrict__ h0, u64* __restrict__ hx2,
                       int* __restrict__ rdy){
  int tid = threadIdx.x;
  if (tid < 1024){
    int dir = tid >> 9, u = tid & 511;
    hx2[(dir*2 + 0)*HH + u] = pack_pair(h0[dir*HH + u], 0u);
    hx2[(dir*2 + 1)*HH + u] = pack_pair(0.f, 0xFFFFFFFFu);
  }
  if (tid < 64) rdy[tid] = 0;
}

// ---------------- fused persistent BiLSTM + input-projection GEMM ----------------
// blocks 0..63: lstm role (R8 structure, validated). blocks 64..1087: inproj
// GEMM role (512-thread variant). Sync via per-(dir,t_tile) ready counters.
__global__ __launch_bounds__(512) void k_fused(
    const int* __restrict__ sent, const float* __restrict__ emb,
    const float* __restrict__ Wif, const float* __restrict__ bf,
    const float* __restrict__ Wib, const float* __restrict__ bb,
    const float* __restrict__ Whf, const float* __restrict__ Whb,
    const float* __restrict__ c0,
    float* __restrict__ A, float* __restrict__ hseq,
    u64* __restrict__ hx2, int* __restrict__ rdy){
  __shared__ __align__(16) char smem[17408];
  const int tid = threadIdx.x;

  if (blockIdx.x >= LSTM_WGS){
    // ================= inproj GEMM role =================
    float (*As)[132] = (float(*)[132])smem;              // 16 x 132
    float (*Bs)[132] = (float(*)[132])(smem + 8448);     // 16 x 132
    int* srow        = (int*)(smem + 16896);             // 128
    const int p   = blockIdx.x - LSTM_WGS;               // 0..1023
    const int ti  = p >> 5;                              // 0..31
    const int yy  = p & 31;                              // 0..31
    const int dir = yy >> 4;
    const int t_tile = dir ? (31 - ti) : ti;             // two-ended production
    const int t0  = t_tile * 128;
    const int n0  = (yy & 15) * 128;
    const float* __restrict__ W    = dir ? Wib : Wif;
    const float* __restrict__ bias = dir ? bb : bf;
    if (tid < 128) srow[tid] = sent[t0 + tid];
    __syncthreads();
    const int lr = tid >> 2;            // 0..127
    const int kq = (tid & 3) * 4;
    const float* ea = emb + (size_t)srow[lr]   * EMBD + kq;
    const float* wb = W + (size_t)(n0 + lr)    * EMBD + kq;
    const int tx = tid & 15, ty = tid >> 4;   // ty 0..31
    float acc[4][8];
    #pragma unroll
    for (int i = 0; i < 4; i++)
      #pragma unroll
      for (int j = 0; j < 8; j++) acc[i][j] = 0.f;

    for (int k0 = 0; k0 < EMBD; k0 += 16){
      float4 va = *(const float4*)(ea + k0);
      float4 vb = *(const float4*)(wb + k0);
      As[kq+0][lr] = va.x; As[kq+1][lr] = va.y; As[kq+2][lr] = va.z; As[kq+3][lr] = va.w;
      Bs[kq+0][lr] = vb.x; Bs[kq+1][lr] = vb.y; Bs[kq+2][lr] = vb.z; Bs[kq+3][lr] = vb.w;
      __syncthreads();
      #pragma unroll
      for (int k = 0; k < 16; k++){
        float a[4], b[8];
        *(float4*)&a[0] = *(const float4*)&As[k][ty*4];
        #pragma unroll
        for (int j = 0; j < 8; j++) b[j] = Bs[k][tx + 16*j];
        #pragma unroll
        for (int i = 0; i < 4; i++)
          #pragma unroll
          for (int j = 0; j < 8; j++)
            acc[i][j] = fmaf(a[i], b[j], acc[i][j]);
      }
      __syncthreads();
    }
    float bj[8];
    #pragma unroll
    for (int j = 0; j < 8; j++) bj[j] = bias[n0 + tx + 16*j];
    float* Abase = A + (size_t)dir * TSEQ * NGATE;
    #pragma unroll
    for (int i = 0; i < 4; i++){
      float* dst = Abase + (size_t)(t0 + ty*4 + i) * NGATE + n0 + tx;
      #pragma unroll
      for (int j = 0; j < 8; j++) dst[16*j] = acc[i][j] + bj[j];
    }
    __syncthreads();   // drains every wave's stores (HIP barrier semantics)
    if (tid == 0)
      __hip_atomic_fetch_add(&rdy[dir*32 + t_tile], 1,
                             __ATOMIC_RELEASE, __HIP_MEMORY_SCOPE_AGENT);
    return;
  }

  // ================= persistent lstm role (R8, validated) =================
  float* hlbuf = (float*)smem;                 // [2][8*68]
  const int bid  = blockIdx.x;
  const int dir  = bid >> 5;
  const int wg   = bid & 31;
  const int lane = tid & 63;
  const int wv   = tid >> 6;        // wave 0..7 = slice index
  const int ul   = tid >> 5;        // unit local 0..15
  const int g    = (tid >> 3) & 3;  // gate i,f,g,o
  const int q    = tid & 7;         // column octant
  const int unit = wg*16 + ul;
  const float* __restrict__ Wh = dir ? Whb : Whf;

  float wreg[64];                   // Wh[g*512+unit][q*64 .. q*64+63]
  {
    const float* wr = Wh + (size_t)(g*HH + unit)*HH + q*64;
    #pragma unroll
    for (int j4 = 0; j4 < 16; j4++){
      float4 vv = *(const float4*)(wr + 4*j4);
      wreg[4*j4+0]=vv.x; wreg[4*j4+1]=vv.y; wreg[4*j4+2]=vv.z; wreg[4*j4+3]=vv.w;
    }
  }
  float creg = 0.f;
  if (g == 0 && q == 0) creg = c0[dir*HH + unit];

  u64* mb = hx2 + (size_t)dir*2*HH;
  const float* __restrict__ Ab = A + (size_t)dir*TSEQ*NGATE;
  const int sidx = (wv << 6) + lane;            // this wave's pair index
  int cur_tile = -1;

  for (int s = 0; s < TSEQ; s++){
    const int t = dir ? (TSEQ - 1 - s) : s;
    // gate on this tile's input-projection readiness (once per 128 steps)
    const int tile = t >> 7;
    if (tile != cur_tile){
      cur_tile = tile;
      const int* rf = rdy + dir*32 + tile;
      while (__hip_atomic_load(rf, __ATOMIC_ACQUIRE, __HIP_MEMORY_SCOPE_AGENT) < 16)
        __builtin_amdgcn_s_sleep(2);
    }
    // prefetch this step's input-projection value (independent load)
    float av = 0.f;
    if (q == 0) av = Ab[(size_t)t*NGATE + g*HH + unit];

    {  // every wave: poll own 64-pair slice (1 load/lane/round, masked reload)
      u64* src = mb + (size_t)(s & 1)*HH;
      const u32 su = (u32)s;
      u64 v = __hip_atomic_load(&src[sidx], __ATOMIC_RELAXED, __HIP_MEMORY_SCOPE_AGENT);
      while (!__all((u32)(v >> 32) == su)){
        if ((u32)(v >> 32) != su)
          v = __hip_atomic_load(&src[sidx], __ATOMIC_RELAXED, __HIP_MEMORY_SCOPE_AGENT);
      }
      hlbuf[(s & 1)*(8*68) + wv*68 + lane] = __uint_as_float((u32)v);
    }
    __syncthreads();

    // matvec: 64 FMAs from LDS chunk q
    const float* hq = hlbuf + (s & 1)*(8*68) + q*68;
    float p0 = 0.f, p1 = 0.f, p2 = 0.f, p3 = 0.f;
    #pragma unroll
    for (int j4 = 0; j4 < 16; j4++){
      float4 h4 = *(const float4*)(hq + 4*j4);
      p0 = fmaf(wreg[4*j4+0], h4.x, p0);
      p1 = fmaf(wreg[4*j4+1], h4.y, p1);
      p2 = fmaf(wreg[4*j4+2], h4.z, p2);
      p3 = fmaf(wreg[4*j4+3], h4.w, p3);
    }
    float acc = ((p0 + p1) + (p2 + p3)) + av;
    acc += __shfl_xor(acc, 1);
    acc += __shfl_xor(acc, 2);
    acc += __shfl_xor(acc, 4);
    // parallel nonlinearity: one transcendental per gate lane
    const float act = (g == 2) ? tanhf(acc) : sigm(acc);
    const float f_ = __shfl_down(act, 8);
    const float g_ = __shfl_down(act, 16);
    const float o_ = __shfl_down(act, 24);
    if (g == 0 && q == 0){
      const float c2 = f_*creg + act*g_;
      const float h2 = o_*tanhf(c2);
      creg = c2;
      // publish FIRST (critical path), bookkeeping store after
      __hip_atomic_store(&mb[(size_t)((s + 1) & 1)*HH + unit], pack_pair(h2, (u32)(s + 1)),
                         __ATOMIC_RELAXED, __HIP_MEMORY_SCOPE_AGENT);
      hseq[((size_t)dir*TSEQ + t)*HH + unit] = h2;
    }
  }
}

// ---------------- emission features: feats[t][n] = lstm_out[t] . W_out[n] + b ----
__global__ __launch_bounds__(64) void k_feats(
    const float* __restrict__ Wout, const float* __restrict__ bout,
    const float* __restrict__ hseq, float* __restrict__ feats){
  const int t = blockIdx.x, lane = threadIdx.x;
  const float* hf = hseq + (size_t)t*HH;
  const float* hb = hseq + (size_t)(TSEQ + t)*HH;
  float x[16];
  #pragma unroll
  for (int k = 0; k < 8; k++) x[k]     = hf[lane + 64*k];
  #pragma unroll
  for (int k = 0; k < 8; k++) x[8 + k] = hb[lane + 64*k];
  #pragma unroll
  for (int n = 0; n < NTAGS; n++){
    const float* wr = Wout + (size_t)n*(2*HH);
    float p = 0.f;
    #pragma unroll
    for (int k = 0; k < 8; k++) p = fmaf(x[k],     wr[lane + 64*k],      p);
    #pragma unroll
    for (int k = 0; k < 8; k++) p = fmaf(x[8 + k], wr[HH + lane + 64*k], p);
    #pragma unroll
    for (int d = 1; d < 64; d <<= 1) p += __shfl_xor(p, d);
    if (lane == 0) feats[t*8 + n] = p + bout[n];
  }
}

// ---------------- Viterbi forward + backtrack: scalar-in-lane, no cross-lane ----
// All 64 lanes execute identical scalar code on uniform addresses (broadcast
// loads); lane 0 does the stores. The 5-tag trellis lives entirely in one
// lane's registers: 25 T values + 5 fv. Per step ~90 VALU ops with ILP across
// the 5 independent 'to' computations — no ds_bpermute anywhere (the old
// version's 9 shuffles/step x 4096 steps was ~1.3 ms). Arithmetic (add order,
// first-max tie-break, feat add) is bit-identical to the previous version.
__global__ __launch_bounds__(64) void k_viterbi(
    const float* __restrict__ trans, const float* __restrict__ feats,
    int* __restrict__ bpw, float* __restrict__ out){
  const int lane = threadIdx.x;
  // T[to][from]
  float T[5][5];
  #pragma unroll
  for (int a = 0; a < 5; a++)
    #pragma unroll
    for (int b = 0; b < 5; b++) T[a][b] = trans[a*NTAGS + b];
  float fv0 = NEGV, fv1 = NEGV, fv2 = NEGV, fv3 = 0.f, fv4 = NEGV; // START=3

  for (int t0 = 0; t0 < TSEQ; t0 += 16){
    float4 fA[16]; float fE[16];
    #pragma unroll
    for (int i = 0; i < 16; i++){
      fA[i] = *(const float4*)(feats + (t0 + i)*8);
      fE[i] = feats[(t0 + i)*8 + 4];
    }
    #pragma unroll
    for (int i = 0; i < 16; i++){
      float nf[5]; int pack = 0;
      #pragma unroll
      for (int to = 0; to < 5; to++){
        const float n0 = fv0 + T[to][0];
        const float n1 = fv1 + T[to][1];
        const float n2 = fv2 + T[to][2];
        const float n3 = fv3 + T[to][3];
        const float n4 = fv4 + T[to][4];
        const float m  = fmaxf(fmaxf(fmaxf(n0, n1), fmaxf(n2, n3)), n4);
        const int idx  = (n0 == m) ? 0 : ((n1 == m) ? 1 : ((n2 == m) ? 2 : ((n3 == m) ? 3 : 4)));
        const float ft = (to == 0) ? fA[i].x : (to == 1) ? fA[i].y :
                         (to == 2) ? fA[i].z : (to == 3) ? fA[i].w : fE[i];
        nf[to] = m + ft;
        pack |= idx << (4*to);
      }
      fv0 = nf[0]; fv1 = nf[1]; fv2 = nf[2]; fv3 = nf[3]; fv4 = nf[4];
      if (lane == 0) bpw[t0 + i] = pack;
    }
  }
  // terminal: fv + T[STOP][from], first-max argmax
  {
    const float n0 = fv0 + T[STOP_TAG][0];
    const float n1 = fv1 + T[STOP_TAG][1];
    const float n2 = fv2 + T[STOP_TAG][2];
    const float n3 = fv3 + T[STOP_TAG][3];
    const float n4 = fv4 + T[STOP_TAG][4];
    const float m  = fmaxf(fmaxf(fmaxf(n0, n1), fmaxf(n2, n3)), n4);
    const int btag = (n0 == m) ? 0 : ((n1 == m) ? 1 : ((n2 == m) ? 2 : ((n3 == m) ? 3 : 4)));
    if (lane == 0){ out[0] = m; out[TSEQ] = (float)btag; }
    // backtrack: blocks of 16 prefetched bpw words, dependent nibble chain
    int tag = btag;
    for (int tb = TSEQ - 1; tb >= 1; tb -= 16){
      int w[16];
      #pragma unroll
      for (int i = 0; i < 16; i++){
        const int t = tb - i;
        w[i] = (t >= 1) ? bpw[t] : 0;
      }
      #pragma unroll
      for (int i = 0; i < 16; i++){
        const int t = tb - i;
        if (t >= 1){
          const int prev = (w[i] >> (tag*4)) & 15;
          if (lane == 0) out[t] = (float)prev;
          tag = prev;
        }
      }
    }
  }
}

extern "C" void kernel_launch(void* const* d_in, const int* in_sizes, int n_in,
                              void* d_out, int out_size, void* d_ws, size_t ws_size,
                              hipStream_t stream) {
  const int*   sent = (const int*)  d_in[0];
  const float* emb  = (const float*)d_in[1];
  const float* Wihf = (const float*)d_in[2];
  const float* Whhf = (const float*)d_in[3];
  const float* bf_  = (const float*)d_in[4];
  const float* Wihb = (const float*)d_in[5];
  const float* Whhb = (const float*)d_in[6];
  const float* bb_  = (const float*)d_in[7];
  const float* Wout = (const float*)d_in[8];
  const float* bout = (const float*)d_in[9];
  const float* trans= (const float*)d_in[10];
  const float* h0   = (const float*)d_in[11];
  const float* c0   = (const float*)d_in[12];
  float* out = (float*)d_out;

  float* ws   = (float*)d_ws;
  float* A    = ws;                                  // [2][T][2048]
  float* hseq = A    + (size_t)2*TSEQ*NGATE;         // [2][T][512]
  u64*   hx2  = (u64*)(hseq + (size_t)2*TSEQ*HH);    // [2][2][512] (tag,val) pairs
  float* fe   = (float*)(hx2 + 2048);                // [T][8]
  int*   bpw  = (int*)(fe + (size_t)TSEQ*8);         // [T] packed nibbles
  int*   rdy  = bpw + TSEQ;                          // [2][32] tile-ready counters
  (void)ws_size;

  k_init<<<1, 1024, 0, stream>>>(h0, hx2, rdy);
  k_fused<<<LSTM_WGS + PROJ_WGS, 512, 0, stream>>>(
      sent, emb, Wihf, bf_, Wihb, bb_, Whhf, Whhb, c0, A, hseq, hx2, rdy);
  k_feats<<<TSEQ, 64, 0, stream>>>(Wout, bout, hseq, fe);
  k_viterbi<<<1, 64, 0, stream>>>(trans, fe, bpw, out);
}

// Round 11
// 9609.655 us; speedup vs baseline: 187.2767x; 1.0334x over previous
//
#include <hip/hip_runtime.h>
#include <hip/hip_bf16.h>
#include <math.h>

#define TSEQ 4096
#define EMBD 1024
#define HH   512
#define NTAGS 5
#define NGATE 2048
#define NEGV (-10000.0f)
#define START_TAG 3
#define STOP_TAG 4
#define LSTM_WGS 64
#define PROJ_WGS 1024
#define FEAT_WGS 512

typedef unsigned long long u64;
typedef unsigned int u32;

__device__ __forceinline__ float sigm(float x){ return 1.0f/(1.0f+expf(-x)); }

__device__ __forceinline__ u64 pack_pair(float h, u32 tag){
  return ((u64)tag << 32) | (u64)__float_as_uint(h);
}

// ---------------- init: prime h pair buffers + zero control counters ----------
__global__ void k_init(const float* __restrict__ h0, u64* __restrict__ hx2,
                       int* __restrict__ rdy){
  int tid = threadIdx.x;
  if (tid < 1024){
    int dir = tid >> 9, u = tid & 511;
    hx2[(dir*2 + 0)*HH + u] = pack_pair(h0[dir*HH + u], 0u);
    hx2[(dir*2 + 1)*HH + u] = pack_pair(0.f, 0xFFFFFFFFu);
  }
  if (tid < 80) rdy[tid] = 0;     // [0..63] tile-ready, [64] feats-done counter
}

// ---------------- fused persistent BiLSTM + input-projection GEMM ----------------
// blocks 0..63: lstm role. blocks 64..1087: inproj GEMM role.
// __launch_bounds__(512, 2): 2 waves/EU = 8 waves/CU -> 256-VGPR budget so the
// lstm role's 64 weight f32/thread STAY IN REGISTERS (R10's VGPR_Count=52
// showed the compiler was reloading them from memory every step). GEMM role
// drops to 1 block/CU but has ~6ms slack under the 8.2ms recurrence.
__global__ __launch_bounds__(512, 2) void k_fused(
    const int* __restrict__ sent, const float* __restrict__ emb,
    const float* __restrict__ Wif, const float* __restrict__ bf,
    const float* __restrict__ Wib, const float* __restrict__ bb,
    const float* __restrict__ Whf, const float* __restrict__ Whb,
    const float* __restrict__ c0,
    float* __restrict__ A, float* __restrict__ hseq,
    u64* __restrict__ hx2, int* __restrict__ rdy){
  __shared__ __align__(16) char smem[17408];
  const int tid = threadIdx.x;

  if (blockIdx.x >= LSTM_WGS){
    // ================= inproj GEMM role =================
    float (*As)[132] = (float(*)[132])smem;              // 16 x 132
    float (*Bs)[132] = (float(*)[132])(smem + 8448);     // 16 x 132
    int* srow        = (int*)(smem + 16896);             // 128
    const int p   = blockIdx.x - LSTM_WGS;               // 0..1023
    const int ti  = p >> 5;                              // 0..31
    const int yy  = p & 31;                              // 0..31
    const int dir = yy >> 4;
    const int t_tile = dir ? (31 - ti) : ti;             // two-ended production
    const int t0  = t_tile * 128;
    const int n0  = (yy & 15) * 128;
    const float* __restrict__ W    = dir ? Wib : Wif;
    const float* __restrict__ bias = dir ? bb : bf;
    if (tid < 128) srow[tid] = sent[t0 + tid];
    __syncthreads();
    const int lr = tid >> 2;            // 0..127
    const int kq = (tid & 3) * 4;
    const float* ea = emb + (size_t)srow[lr]   * EMBD + kq;
    const float* wb = W + (size_t)(n0 + lr)    * EMBD + kq;
    const int tx = tid & 15, ty = tid >> 4;   // ty 0..31
    float acc[4][8];
    #pragma unroll
    for (int i = 0; i < 4; i++)
      #pragma unroll
      for (int j = 0; j < 8; j++) acc[i][j] = 0.f;

    for (int k0 = 0; k0 < EMBD; k0 += 16){
      float4 va = *(const float4*)(ea + k0);
      float4 vb = *(const float4*)(wb + k0);
      As[kq+0][lr] = va.x; As[kq+1][lr] = va.y; As[kq+2][lr] = va.z; As[kq+3][lr] = va.w;
      Bs[kq+0][lr] = vb.x; Bs[kq+1][lr] = vb.y; Bs[kq+2][lr] = vb.z; Bs[kq+3][lr] = vb.w;
      __syncthreads();
      #pragma unroll
      for (int k = 0; k < 16; k++){
        float a[4], b[8];
        *(float4*)&a[0] = *(const float4*)&As[k][ty*4];
        #pragma unroll
        for (int j = 0; j < 8; j++) b[j] = Bs[k][tx + 16*j];
        #pragma unroll
        for (int i = 0; i < 4; i++)
          #pragma unroll
          for (int j = 0; j < 8; j++)
            acc[i][j] = fmaf(a[i], b[j], acc[i][j]);
      }
      __syncthreads();
    }
    float bj[8];
    #pragma unroll
    for (int j = 0; j < 8; j++) bj[j] = bias[n0 + tx + 16*j];
    float* Abase = A + (size_t)dir * TSEQ * NGATE;
    #pragma unroll
    for (int i = 0; i < 4; i++){
      float* dst = Abase + (size_t)(t0 + ty*4 + i) * NGATE + n0 + tx;
      #pragma unroll
      for (int j = 0; j < 8; j++) dst[16*j] = acc[i][j] + bj[j];
    }
    __syncthreads();   // drains every wave's stores (HIP barrier semantics)
    if (tid == 0)
      __hip_atomic_fetch_add(&rdy[dir*32 + t_tile], 1,
                             __ATOMIC_RELEASE, __HIP_MEMORY_SCOPE_AGENT);
    return;
  }

  // ================= persistent lstm role (R8 exchange, validated) =========
  float* hlbuf = (float*)smem;                 // [2][8*68]
  const int bid  = blockIdx.x;
  const int dir  = bid >> 5;
  const int wg   = bid & 31;
  const int lane = tid & 63;
  const int wv   = tid >> 6;        // wave 0..7 = slice index
  const int ul   = tid >> 5;        // unit local 0..15
  const int g    = (tid >> 3) & 3;  // gate i,f,g,o
  const int q    = tid & 7;         // column octant
  const int unit = wg*16 + ul;
  const float* __restrict__ Wh = dir ? Whb : Whf;

  float wreg[64];                   // Wh[g*512+unit][q*64 .. q*64+63]
  {
    const float* wr = Wh + (size_t)(g*HH + unit)*HH + q*64;
    #pragma unroll
    for (int j4 = 0; j4 < 16; j4++){
      float4 vv = *(const float4*)(wr + 4*j4);
      wreg[4*j4+0]=vv.x; wreg[4*j4+1]=vv.y; wreg[4*j4+2]=vv.z; wreg[4*j4+3]=vv.w;
    }
  }
  float creg = 0.f;
  if (g == 0 && q == 0) creg = c0[dir*HH + unit];

  u64* mb = hx2 + (size_t)dir*2*HH;
  const float* __restrict__ Ab = A + (size_t)dir*TSEQ*NGATE;
  const int sidx = (wv << 6) + lane;            // this wave's pair index
  int cur_tile = -1;

  for (int s = 0; s < TSEQ; s++){
    const int t = dir ? (TSEQ - 1 - s) : s;
    // gate on this tile's input-projection readiness (once per 128 steps)
    const int tile = t >> 7;
    if (tile != cur_tile){
      cur_tile = tile;
      const int* rf = rdy + dir*32 + tile;
      while (__hip_atomic_load(rf, __ATOMIC_ACQUIRE, __HIP_MEMORY_SCOPE_AGENT) < 16)
        __builtin_amdgcn_s_sleep(2);
    }
    // prefetch this step's input-projection value (independent load)
    float av = 0.f;
    if (q == 0) av = Ab[(size_t)t*NGATE + g*HH + unit];

    {  // every wave: poll own 64-pair slice (1 load/lane/round, masked reload)
      u64* src = mb + (size_t)(s & 1)*HH;
      const u32 su = (u32)s;
      u64 v = __hip_atomic_load(&src[sidx], __ATOMIC_RELAXED, __HIP_MEMORY_SCOPE_AGENT);
      while (!__all((u32)(v >> 32) == su)){
        if ((u32)(v >> 32) != su)
          v = __hip_atomic_load(&src[sidx], __ATOMIC_RELAXED, __HIP_MEMORY_SCOPE_AGENT);
      }
      hlbuf[(s & 1)*(8*68) + wv*68 + lane] = __uint_as_float((u32)v);
    }
    __syncthreads();

    // matvec: 64 FMAs from LDS chunk q (weights now register-resident)
    const float* hq = hlbuf + (s & 1)*(8*68) + q*68;
    float p0 = 0.f, p1 = 0.f, p2 = 0.f, p3 = 0.f;
    #pragma unroll
    for (int j4 = 0; j4 < 16; j4++){
      float4 h4 = *(const float4*)(hq + 4*j4);
      p0 = fmaf(wreg[4*j4+0], h4.x, p0);
      p1 = fmaf(wreg[4*j4+1], h4.y, p1);
      p2 = fmaf(wreg[4*j4+2], h4.z, p2);
      p3 = fmaf(wreg[4*j4+3], h4.w, p3);
    }
    float acc = ((p0 + p1) + (p2 + p3)) + av;
    acc += __shfl_xor(acc, 1);
    acc += __shfl_xor(acc, 2);
    acc += __shfl_xor(acc, 4);
    // parallel nonlinearity: one transcendental per gate lane
    const float act = (g == 2) ? tanhf(acc) : sigm(acc);
    const float f_ = __shfl_down(act, 8);
    const float g_ = __shfl_down(act, 16);
    const float o_ = __shfl_down(act, 24);
    if (g == 0 && q == 0){
      const float c2 = f_*creg + act*g_;
      const float h2 = o_*tanhf(c2);
      creg = c2;
      // publish FIRST (critical path), bookkeeping store after
      __hip_atomic_store(&mb[(size_t)((s + 1) & 1)*HH + unit], pack_pair(h2, (u32)(s + 1)),
                         __ATOMIC_RELAXED, __HIP_MEMORY_SCOPE_AGENT);
      hseq[((size_t)dir*TSEQ + t)*HH + unit] = h2;
    }
  }
}

// ---------------- merged tail: emission features + Viterbi ----------------
// blocks 0..511: feats role (wave w computes t = 8*blk + w). block 512:
// viterbi role — ACQUIRE-polls the feats-done counter (==512), then runs the
// scalar-in-lane Viterbi (R10 version, validated bit-exact). Removes one
// kernel launch and serializes internally via release/acquire counter.
__global__ __launch_bounds__(512) void k_tail(
    const float* __restrict__ Wout, const float* __restrict__ bout,
    const float* __restrict__ hseq, const float* __restrict__ trans,
    float* __restrict__ feats, int* __restrict__ bpw,
    float* __restrict__ out, int* __restrict__ fcnt){
  const int tid = threadIdx.x;
  if (blockIdx.x < FEAT_WGS){
    const int wvi = tid >> 6, lane = tid & 63;
    const int t = blockIdx.x*8 + wvi;
    const float* hf = hseq + (size_t)t*HH;
    const float* hb = hseq + (size_t)(TSEQ + t)*HH;
    float x[16];
    #pragma unroll
    for (int k = 0; k < 8; k++) x[k]     = hf[lane + 64*k];
    #pragma unroll
    for (int k = 0; k < 8; k++) x[8 + k] = hb[lane + 64*k];
    #pragma unroll
    for (int n = 0; n < NTAGS; n++){
      const float* wr = Wout + (size_t)n*(2*HH);
      float p = 0.f;
      #pragma unroll
      for (int k = 0; k < 8; k++) p = fmaf(x[k],     wr[lane + 64*k],      p);
      #pragma unroll
      for (int k = 0; k < 8; k++) p = fmaf(x[8 + k], wr[HH + lane + 64*k], p);
      #pragma unroll
      for (int d = 1; d < 64; d <<= 1) p += __shfl_xor(p, d);
      if (lane == 0) feats[t*8 + n] = p + bout[n];
    }
    __syncthreads();   // all waves' feats stores done
    if (tid == 0)
      __hip_atomic_fetch_add(fcnt, 1, __ATOMIC_RELEASE, __HIP_MEMORY_SCOPE_AGENT);
    return;
  }
  // ---------------- viterbi role ----------------
  if (tid >= 64) return;   // single wave; no barriers below
  const int lane = tid;
  while (__hip_atomic_load(fcnt, __ATOMIC_ACQUIRE, __HIP_MEMORY_SCOPE_AGENT) < FEAT_WGS)
    __builtin_amdgcn_s_sleep(8);

  float T[5][5];
  #pragma unroll
  for (int a = 0; a < 5; a++)
    #pragma unroll
    for (int b = 0; b < 5; b++) T[a][b] = trans[a*NTAGS + b];
  float fv0 = NEGV, fv1 = NEGV, fv2 = NEGV, fv3 = 0.f, fv4 = NEGV; // START=3

  for (int t0 = 0; t0 < TSEQ; t0 += 16){
    float4 fA[16]; float fE[16];
    #pragma unroll
    for (int i = 0; i < 16; i++){
      fA[i] = *(const float4*)(feats + (t0 + i)*8);
      fE[i] = feats[(t0 + i)*8 + 4];
    }
    #pragma unroll
    for (int i = 0; i < 16; i++){
      float nf[5]; int pack = 0;
      #pragma unroll
      for (int to = 0; to < 5; to++){
        const float n0 = fv0 + T[to][0];
        const float n1 = fv1 + T[to][1];
        const float n2 = fv2 + T[to][2];
        const float n3 = fv3 + T[to][3];
        const float n4 = fv4 + T[to][4];
        const float m  = fmaxf(fmaxf(fmaxf(n0, n1), fmaxf(n2, n3)), n4);
        const int idx  = (n0 == m) ? 0 : ((n1 == m) ? 1 : ((n2 == m) ? 2 : ((n3 == m) ? 3 : 4)));
        const float ft = (to == 0) ? fA[i].x : (to == 1) ? fA[i].y :
                         (to == 2) ? fA[i].z : (to == 3) ? fA[i].w : fE[i];
        nf[to] = m + ft;
        pack |= idx << (4*to);
      }
      fv0 = nf[0]; fv1 = nf[1]; fv2 = nf[2]; fv3 = nf[3]; fv4 = nf[4];
      if (lane == 0) bpw[t0 + i] = pack;
    }
  }
  {
    const float n0 = fv0 + T[STOP_TAG][0];
    const float n1 = fv1 + T[STOP_TAG][1];
    const float n2 = fv2 + T[STOP_TAG][2];
    const float n3 = fv3 + T[STOP_TAG][3];
    const float n4 = fv4 + T[STOP_TAG][4];
    const float m  = fmaxf(fmaxf(fmaxf(n0, n1), fmaxf(n2, n3)), n4);
    const int btag = (n0 == m) ? 0 : ((n1 == m) ? 1 : ((n2 == m) ? 2 : ((n3 == m) ? 3 : 4)));
    if (lane == 0){ out[0] = m; out[TSEQ] = (float)btag; }
    int tag = btag;
    for (int tb = TSEQ - 1; tb >= 1; tb -= 16){
      int w[16];
      #pragma unroll
      for (int i = 0; i < 16; i++){
        const int t = tb - i;
        w[i] = (t >= 1) ? bpw[t] : 0;
      }
      #pragma unroll
      for (int i = 0; i < 16; i++){
        const int t = tb - i;
        if (t >= 1){
          const int prev = (w[i] >> (tag*4)) & 15;
          if (lane == 0) out[t] = (float)prev;
          tag = prev;
        }
      }
    }
  }
}

extern "C" void kernel_launch(void* const* d_in, const int* in_sizes, int n_in,
                              void* d_out, int out_size, void* d_ws, size_t ws_size,
                              hipStream_t stream) {
  const int*   sent = (const int*)  d_in[0];
  const float* emb  = (const float*)d_in[1];
  const float* Wihf = (const float*)d_in[2];
  const float* Whhf = (const float*)d_in[3];
  const float* bf_  = (const float*)d_in[4];
  const float* Wihb = (const float*)d_in[5];
  const float* Whhb = (const float*)d_in[6];
  const float* bb_  = (const float*)d_in[7];
  const float* Wout = (const float*)d_in[8];
  const float* bout = (const float*)d_in[9];
  const float* trans= (const float*)d_in[10];
  const float* h0   = (const float*)d_in[11];
  const float* c0   = (const float*)d_in[12];
  float* out = (float*)d_out;

  float* ws   = (float*)d_ws;
  float* A    = ws;                                  // [2][T][2048]
  float* hseq = A    + (size_t)2*TSEQ*NGATE;         // [2][T][512]
  u64*   hx2  = (u64*)(hseq + (size_t)2*TSEQ*HH);    // [2][2][512] (tag,val) pairs
  float* fe   = (float*)(hx2 + 2048);                // [T][8]
  int*   bpw  = (int*)(fe + (size_t)TSEQ*8);         // [T] packed nibbles
  int*   rdy  = bpw + TSEQ;                          // [64] tile-ready + [64] fcnt
  int*   fcnt = rdy + 64;
  (void)ws_size;

  k_init<<<1, 1024, 0, stream>>>(h0, hx2, rdy);
  k_fused<<<LSTM_WGS + PROJ_WGS, 512, 0, stream>>>(
      sent, emb, Wihf, bf_, Wihb, bb_, Whhf, Whhb, c0, A, hseq, hx2, rdy);
  k_tail<<<FEAT_WGS + 1, 512, 0, stream>>>(Wout, bout, hseq, trans, fe, bpw, out, fcnt);
}

// Round 12
// 9568.389 us; speedup vs baseline: 188.0844x; 1.0043x over previous
//
#include <hip/hip_runtime.h>
#include <hip/hip_bf16.h>
#include <math.h>

#define TSEQ 4096
#define EMBD 1024
#define HH   512
#define NTAGS 5
#define NGATE 2048
#define NEGV (-10000.0f)
#define START_TAG 3
#define STOP_TAG 4
#define LSTM_WGS 64
#define PROJ_WGS 1024
#define FEAT_WGS 512

typedef unsigned long long u64;
typedef unsigned int u32;

__device__ __forceinline__ float sigm(float x){ return 1.0f/(1.0f+expf(-x)); }

__device__ __forceinline__ u64 pack_pair(float h, u32 tag){
  return ((u64)tag << 32) | (u64)__float_as_uint(h);
}

// ---------------- init: prime h pair buffers + zero control counters ----------
__global__ void k_init(const float* __restrict__ h0, u64* __restrict__ hx2,
                       int* __restrict__ rdy){
  int tid = threadIdx.x;
  if (tid < 1024){
    int dir = tid >> 9, u = tid & 511;
    hx2[(dir*2 + 0)*HH + u] = pack_pair(h0[dir*HH + u], 0u);
    hx2[(dir*2 + 1)*HH + u] = pack_pair(0.f, 0xFFFFFFFFu);
  }
  if (tid < 80) rdy[tid] = 0;     // [0..63] tile-ready, [64] feats-done counter
}

// ---------------- fused persistent BiLSTM + input-projection GEMM ----------------
// blocks 0..63: lstm role. blocks 64..1087: inproj GEMM role.
// R12: (1) wreg keep-alive asm — R10/R11's VGPR_Count=52 proved the allocator
// rematerializes the 64 weight floats from memory EVERY STEP (16 dwordx4 L2
// loads on the serial path); opaque "+v" asm forces them register-resident.
// (2) A-value prefetch pipelined one step ahead so its HBM latency resolves
// under the matvec instead of inside the poll's vmcnt(0) wait.
__global__ __launch_bounds__(512, 2) void k_fused(
    const int* __restrict__ sent, const float* __restrict__ emb,
    const float* __restrict__ Wif, const float* __restrict__ bf,
    const float* __restrict__ Wib, const float* __restrict__ bb,
    const float* __restrict__ Whf, const float* __restrict__ Whb,
    const float* __restrict__ c0,
    float* __restrict__ A, float* __restrict__ hseq,
    u64* __restrict__ hx2, int* __restrict__ rdy){
  __shared__ __align__(16) char smem[17408];
  const int tid = threadIdx.x;

  if (blockIdx.x >= LSTM_WGS){
    // ================= inproj GEMM role =================
    float (*As)[132] = (float(*)[132])smem;              // 16 x 132
    float (*Bs)[132] = (float(*)[132])(smem + 8448);     // 16 x 132
    int* srow        = (int*)(smem + 16896);             // 128
    const int p   = blockIdx.x - LSTM_WGS;               // 0..1023
    const int ti  = p >> 5;                              // 0..31
    const int yy  = p & 31;                              // 0..31
    const int dir = yy >> 4;
    const int t_tile = dir ? (31 - ti) : ti;             // two-ended production
    const int t0  = t_tile * 128;
    const int n0  = (yy & 15) * 128;
    const float* __restrict__ W    = dir ? Wib : Wif;
    const float* __restrict__ bias = dir ? bb : bf;
    if (tid < 128) srow[tid] = sent[t0 + tid];
    __syncthreads();
    const int lr = tid >> 2;            // 0..127
    const int kq = (tid & 3) * 4;
    const float* ea = emb + (size_t)srow[lr]   * EMBD + kq;
    const float* wb = W + (size_t)(n0 + lr)    * EMBD + kq;
    const int tx = tid & 15, ty = tid >> 4;   // ty 0..31
    float acc[4][8];
    #pragma unroll
    for (int i = 0; i < 4; i++)
      #pragma unroll
      for (int j = 0; j < 8; j++) acc[i][j] = 0.f;

    for (int k0 = 0; k0 < EMBD; k0 += 16){
      float4 va = *(const float4*)(ea + k0);
      float4 vb = *(const float4*)(wb + k0);
      As[kq+0][lr] = va.x; As[kq+1][lr] = va.y; As[kq+2][lr] = va.z; As[kq+3][lr] = va.w;
      Bs[kq+0][lr] = vb.x; Bs[kq+1][lr] = vb.y; Bs[kq+2][lr] = vb.z; Bs[kq+3][lr] = vb.w;
      __syncthreads();
      #pragma unroll
      for (int k = 0; k < 16; k++){
        float a[4], b[8];
        *(float4*)&a[0] = *(const float4*)&As[k][ty*4];
        #pragma unroll
        for (int j = 0; j < 8; j++) b[j] = Bs[k][tx + 16*j];
        #pragma unroll
        for (int i = 0; i < 4; i++)
          #pragma unroll
          for (int j = 0; j < 8; j++)
            acc[i][j] = fmaf(a[i], b[j], acc[i][j]);
      }
      __syncthreads();
    }
    float bj[8];
    #pragma unroll
    for (int j = 0; j < 8; j++) bj[j] = bias[n0 + tx + 16*j];
    float* Abase = A + (size_t)dir * TSEQ * NGATE;
    #pragma unroll
    for (int i = 0; i < 4; i++){
      float* dst = Abase + (size_t)(t0 + ty*4 + i) * NGATE + n0 + tx;
      #pragma unroll
      for (int j = 0; j < 8; j++) dst[16*j] = acc[i][j] + bj[j];
    }
    __syncthreads();   // drains every wave's stores (HIP barrier semantics)
    if (tid == 0)
      __hip_atomic_fetch_add(&rdy[dir*32 + t_tile], 1,
                             __ATOMIC_RELEASE, __HIP_MEMORY_SCOPE_AGENT);
    return;
  }

  // ================= persistent lstm role =================
  float* hlbuf = (float*)smem;                 // [2][8*68]
  const int bid  = blockIdx.x;
  const int dir  = bid >> 5;
  const int wg   = bid & 31;
  const int lane = tid & 63;
  const int wv   = tid >> 6;        // wave 0..7 = slice index
  const int ul   = tid >> 5;        // unit local 0..15
  const int g    = (tid >> 3) & 3;  // gate i,f,g,o
  const int q    = tid & 7;         // column octant
  const int unit = wg*16 + ul;
  const float* __restrict__ Wh = dir ? Whb : Whf;

  float wreg[64];                   // Wh[g*512+unit][q*64 .. q*64+63]
  {
    const float* wr = Wh + (size_t)(g*HH + unit)*HH + q*64;
    #pragma unroll
    for (int j4 = 0; j4 < 16; j4++){
      float4 vv = *(const float4*)(wr + 4*j4);
      wreg[4*j4+0]=vv.x; wreg[4*j4+1]=vv.y; wreg[4*j4+2]=vv.z; wreg[4*j4+3]=vv.w;
      // keep-alive: opaque asm pins each weight in a VGPR — the allocator
      // cannot rematerialize past this (R10/R11 reloaded them every step)
      asm volatile("" : "+v"(wreg[4*j4+0]), "+v"(wreg[4*j4+1]),
                        "+v"(wreg[4*j4+2]), "+v"(wreg[4*j4+3]));
    }
  }
  float creg = 0.f;
  if (g == 0 && q == 0) creg = c0[dir*HH + unit];

  u64* mb = hx2 + (size_t)dir*2*HH;
  const float* __restrict__ Ab = A + (size_t)dir*TSEQ*NGATE;
  const int sidx = (wv << 6) + lane;            // this wave's pair index

  // tile-gate + A prefetch for s=0
  int cur_tile = (dir ? (TSEQ - 1) : 0) >> 7;
  {
    const int* rf = rdy + dir*32 + cur_tile;
    while (__hip_atomic_load(rf, __ATOMIC_ACQUIRE, __HIP_MEMORY_SCOPE_AGENT) < 16)
      __builtin_amdgcn_s_sleep(2);
  }
  float av = 0.f;
  if (q == 0) av = Ab[(size_t)(dir ? (TSEQ - 1) : 0)*NGATE + g*HH + unit];

  for (int s = 0; s < TSEQ; s++){
    const int t = dir ? (TSEQ - 1 - s) : s;

    {  // every wave: poll own 64-pair slice (1 load/lane/round, masked reload)
      u64* src = mb + (size_t)(s & 1)*HH;
      const u32 su = (u32)s;
      u64 v = __hip_atomic_load(&src[sidx], __ATOMIC_RELAXED, __HIP_MEMORY_SCOPE_AGENT);
      while (!__all((u32)(v >> 32) == su)){
        if ((u32)(v >> 32) != su)
          v = __hip_atomic_load(&src[sidx], __ATOMIC_RELAXED, __HIP_MEMORY_SCOPE_AGENT);
      }
      hlbuf[(s & 1)*(8*68) + wv*68 + lane] = __uint_as_float((u32)v);
    }
    __syncthreads();

    // prefetch A for step s+1 (resolves under the matvec, off the poll path)
    float av_next = 0.f;
    if (s + 1 < TSEQ){
      const int t1 = dir ? (TSEQ - 2 - s) : (s + 1);
      const int tile1 = t1 >> 7;
      if (tile1 != cur_tile){
        cur_tile = tile1;
        const int* rf = rdy + dir*32 + tile1;
        while (__hip_atomic_load(rf, __ATOMIC_ACQUIRE, __HIP_MEMORY_SCOPE_AGENT) < 16)
          __builtin_amdgcn_s_sleep(2);
      }
      if (q == 0) av_next = Ab[(size_t)t1*NGATE + g*HH + unit];
    }

    // matvec: 64 FMAs from LDS chunk q (weights register-resident)
    const float* hq = hlbuf + (s & 1)*(8*68) + q*68;
    float p0 = 0.f, p1 = 0.f, p2 = 0.f, p3 = 0.f;
    #pragma unroll
    for (int j4 = 0; j4 < 16; j4++){
      float4 h4 = *(const float4*)(hq + 4*j4);
      p0 = fmaf(wreg[4*j4+0], h4.x, p0);
      p1 = fmaf(wreg[4*j4+1], h4.y, p1);
      p2 = fmaf(wreg[4*j4+2], h4.z, p2);
      p3 = fmaf(wreg[4*j4+3], h4.w, p3);
    }
    float acc = ((p0 + p1) + (p2 + p3)) + av;
    acc += __shfl_xor(acc, 1);
    acc += __shfl_xor(acc, 2);
    acc += __shfl_xor(acc, 4);
    // parallel nonlinearity: one transcendental per gate lane
    const float act = (g == 2) ? tanhf(acc) : sigm(acc);
    const float f_ = __shfl_down(act, 8);
    const float g_ = __shfl_down(act, 16);
    const float o_ = __shfl_down(act, 24);
    if (g == 0 && q == 0){
      const float c2 = f_*creg + act*g_;
      const float h2 = o_*tanhf(c2);
      creg = c2;
      // publish FIRST (critical path), bookkeeping store after
      __hip_atomic_store(&mb[(size_t)((s + 1) & 1)*HH + unit], pack_pair(h2, (u32)(s + 1)),
                         __ATOMIC_RELAXED, __HIP_MEMORY_SCOPE_AGENT);
      hseq[((size_t)dir*TSEQ + t)*HH + unit] = h2;
    }
    av = av_next;
  }
}

// ---------------- merged tail: emission features + Viterbi ----------------
__global__ __launch_bounds__(512) void k_tail(
    const float* __restrict__ Wout, const float* __restrict__ bout,
    const float* __restrict__ hseq, const float* __restrict__ trans,
    float* __restrict__ feats, int* __restrict__ bpw,
    float* __restrict__ out, int* __restrict__ fcnt){
  const int tid = threadIdx.x;
  if (blockIdx.x < FEAT_WGS){
    const int wvi = tid >> 6, lane = tid & 63;
    const int t = blockIdx.x*8 + wvi;
    const float* hf = hseq + (size_t)t*HH;
    const float* hb = hseq + (size_t)(TSEQ + t)*HH;
    float x[16];
    #pragma unroll
    for (int k = 0; k < 8; k++) x[k]     = hf[lane + 64*k];
    #pragma unroll
    for (int k = 0; k < 8; k++) x[8 + k] = hb[lane + 64*k];
    #pragma unroll
    for (int n = 0; n < NTAGS; n++){
      const float* wr = Wout + (size_t)n*(2*HH);
      float p = 0.f;
      #pragma unroll
      for (int k = 0; k < 8; k++) p = fmaf(x[k],     wr[lane + 64*k],      p);
      #pragma unroll
      for (int k = 0; k < 8; k++) p = fmaf(x[8 + k], wr[HH + lane + 64*k], p);
      #pragma unroll
      for (int d = 1; d < 64; d <<= 1) p += __shfl_xor(p, d);
      if (lane == 0) feats[t*8 + n] = p + bout[n];
    }
    __syncthreads();   // all waves' feats stores done
    if (tid == 0)
      __hip_atomic_fetch_add(fcnt, 1, __ATOMIC_RELEASE, __HIP_MEMORY_SCOPE_AGENT);
    return;
  }
  // ---------------- viterbi role ----------------
  if (tid >= 64) return;   // single wave; no barriers below
  const int lane = tid;
  while (__hip_atomic_load(fcnt, __ATOMIC_ACQUIRE, __HIP_MEMORY_SCOPE_AGENT) < FEAT_WGS)
    __builtin_amdgcn_s_sleep(8);

  float T[5][5];
  #pragma unroll
  for (int a = 0; a < 5; a++)
    #pragma unroll
    for (int b = 0; b < 5; b++) T[a][b] = trans[a*NTAGS + b];
  float fv0 = NEGV, fv1 = NEGV, fv2 = NEGV, fv3 = 0.f, fv4 = NEGV; // START=3

  for (int t0 = 0; t0 < TSEQ; t0 += 16){
    float4 fA[16]; float fE[16];
    #pragma unroll
    for (int i = 0; i < 16; i++){
      fA[i] = *(const float4*)(feats + (t0 + i)*8);
      fE[i] = feats[(t0 + i)*8 + 4];
    }
    #pragma unroll
    for (int i = 0; i < 16; i++){
      float nf[5]; int pack = 0;
      #pragma unroll
      for (int to = 0; to < 5; to++){
        const float n0 = fv0 + T[to][0];
        const float n1 = fv1 + T[to][1];
        const float n2 = fv2 + T[to][2];
        const float n3 = fv3 + T[to][3];
        const float n4 = fv4 + T[to][4];
        const float m  = fmaxf(fmaxf(fmaxf(n0, n1), fmaxf(n2, n3)), n4);
        const int idx  = (n0 == m) ? 0 : ((n1 == m) ? 1 : ((n2 == m) ? 2 : ((n3 == m) ? 3 : 4)));
        const float ft = (to == 0) ? fA[i].x : (to == 1) ? fA[i].y :
                         (to == 2) ? fA[i].z : (to == 3) ? fA[i].w : fE[i];
        nf[to] = m + ft;
        pack |= idx << (4*to);
      }
      fv0 = nf[0]; fv1 = nf[1]; fv2 = nf[2]; fv3 = nf[3]; fv4 = nf[4];
      if (lane == 0) bpw[t0 + i] = pack;
    }
  }
  {
    const float n0 = fv0 + T[STOP_TAG][0];
    const float n1 = fv1 + T[STOP_TAG][1];
    const float n2 = fv2 + T[STOP_TAG][2];
    const float n3 = fv3 + T[STOP_TAG][3];
    const float n4 = fv4 + T[STOP_TAG][4];
    const float m  = fmaxf(fmaxf(fmaxf(n0, n1), fmaxf(n2, n3)), n4);
    const int btag = (n0 == m) ? 0 : ((n1 == m) ? 1 : ((n2 == m) ? 2 : ((n3 == m) ? 3 : 4)));
    if (lane == 0){ out[0] = m; out[TSEQ] = (float)btag; }
    int tag = btag;
    for (int tb = TSEQ - 1; tb >= 1; tb -= 16){
      int w[16];
      #pragma unroll
      for (int i = 0; i < 16; i++){
        const int t = tb - i;
        w[i] = (t >= 1) ? bpw[t] : 0;
      }
      #pragma unroll
      for (int i = 0; i < 16; i++){
        const int t = tb - i;
        if (t >= 1){
          const int prev = (w[i] >> (tag*4)) & 15;
          if (lane == 0) out[t] = (float)prev;
          tag = prev;
        }
      }
    }
  }
}

extern "C" void kernel_launch(void* const* d_in, const int* in_sizes, int n_in,
                              void* d_out, int out_size, void* d_ws, size_t ws_size,
                              hipStream_t stream) {
  const int*   sent = (const int*)  d_in[0];
  const float* emb  = (const float*)d_in[1];
  const float* Wihf = (const float*)d_in[2];
  const float* Whhf = (const float*)d_in[3];
  const float* bf_  = (const float*)d_in[4];
  const float* Wihb = (const float*)d_in[5];
  const float* Whhb = (const float*)d_in[6];
  const float* bb_  = (const float*)d_in[7];
  const float* Wout = (const float*)d_in[8];
  const float* bout = (const float*)d_in[9];
  const float* trans= (const float*)d_in[10];
  const float* h0   = (const float*)d_in[11];
  const float* c0   = (const float*)d_in[12];
  float* out = (float*)d_out;

  float* ws   = (float*)d_ws;
  float* A    = ws;                                  // [2][T][2048]
  float* hseq = A    + (size_t)2*TSEQ*NGATE;         // [2][T][512]
  u64*   hx2  = (u64*)(hseq + (size_t)2*TSEQ*HH);    // [2][2][512] (tag,val) pairs
  float* fe   = (float*)(hx2 + 2048);                // [T][8]
  int*   bpw  = (int*)(fe + (size_t)TSEQ*8);         // [T] packed nibbles
  int*   rdy  = bpw + TSEQ;                          // [64] tile-ready + fcnt
  int*   fcnt = rdy + 64;
  (void)ws_size;

  k_init<<<1, 1024, 0, stream>>>(h0, hx2, rdy);
  k_fused<<<LSTM_WGS + PROJ_WGS, 512, 0, stream>>>(
      sent, emb, Wihf, bf_, Wihb, bb_, Whhf, Whhb, c0, A, hseq, hx2, rdy);
  k_tail<<<FEAT_WGS + 1, 512, 0, stream>>>(Wout, bout, hseq, trans, fe, bpw, out, fcnt);
}

// Round 13
// 8953.548 us; speedup vs baseline: 201.0001x; 1.0687x over previous
//
#include <hip/hip_runtime.h>
#include <hip/hip_bf16.h>
#include <math.h>

#define TSEQ 4096
#define EMBD 1024
#define HH   512
#define NTAGS 5
#define NGATE 2048
#define NEGV (-10000.0f)
#define START_TAG 3
#define STOP_TAG 4
#define LSTM_WGS 64
#define PROJ_WGS 1024

typedef unsigned long long u64;
typedef unsigned int u32;

__device__ __forceinline__ float sigm(float x){ return 1.0f/(1.0f+expf(-x)); }

__device__ __forceinline__ u64 pack_pair(float h, u32 tag){
  return ((u64)tag << 32) | (u64)__float_as_uint(h);
}

// ---------------- init: prime h pair buffers + zero control counters ----------
__global__ void k_init(const float* __restrict__ h0, u64* __restrict__ hx2,
                       int* __restrict__ rdy){
  int tid = threadIdx.x;
  if (tid < 1024){
    int dir = tid >> 9, u = tid & 511;
    hx2[(dir*2 + 0)*HH + u] = pack_pair(h0[dir*HH + u], 0u);
    hx2[(dir*2 + 1)*HH + u] = pack_pair(0.f, 0xFFFFFFFFu);
  }
  if (tid < 96) rdy[tid] = 0;  // [0..63] tile-ready, [65] lstm-done counter
}

// ---------------- fused persistent BiLSTM + inproj GEMM + feats epilogue --------
// blocks 0..63: lstm role (+ feats epilogue). blocks 64..1087: inproj GEMM.
// R13: weights loaded via VOLATILE inline-asm global_load_dwordx4 — a volatile
// asm result cannot be rematerialized, so the 64 weight floats are forced to
// stay VGPR-resident across the whole step loop (R11/R12's VGPR_Count=52/48
// proved plain loads + keep-alive asm still get re-issued from L2 every step).
// Verification signal: VGPR_Count must jump to >=100.
__global__ __launch_bounds__(512, 2) void k_fused(
    const int* __restrict__ sent, const float* __restrict__ emb,
    const float* __restrict__ Wif, const float* __restrict__ bf,
    const float* __restrict__ Wib, const float* __restrict__ bb,
    const float* __restrict__ Whf, const float* __restrict__ Whb,
    const float* __restrict__ c0, const float* __restrict__ Wout,
    const float* __restrict__ bout,
    float* __restrict__ A, float* __restrict__ hseq, float* __restrict__ feats,
    u64* __restrict__ hx2, int* __restrict__ rdy){
  __shared__ __align__(16) char smem[17408];
  const int tid = threadIdx.x;

  if (blockIdx.x >= LSTM_WGS){
    // ================= inproj GEMM role =================
    float (*As)[132] = (float(*)[132])smem;              // 16 x 132
    float (*Bs)[132] = (float(*)[132])(smem + 8448);     // 16 x 132
    int* srow        = (int*)(smem + 16896);             // 128
    const int p   = blockIdx.x - LSTM_WGS;               // 0..1023
    const int ti  = p >> 5;                              // 0..31
    const int yy  = p & 31;                              // 0..31
    const int dir = yy >> 4;
    const int t_tile = dir ? (31 - ti) : ti;             // two-ended production
    const int t0  = t_tile * 128;
    const int n0  = (yy & 15) * 128;
    const float* __restrict__ W    = dir ? Wib : Wif;
    const float* __restrict__ bias = dir ? bb : bf;
    if (tid < 128) srow[tid] = sent[t0 + tid];
    __syncthreads();
    const int lr = tid >> 2;            // 0..127
    const int kq = (tid & 3) * 4;
    const float* ea = emb + (size_t)srow[lr]   * EMBD + kq;
    const float* wb = W + (size_t)(n0 + lr)    * EMBD + kq;
    const int tx = tid & 15, ty = tid >> 4;   // ty 0..31
    float acc[4][8];
    #pragma unroll
    for (int i = 0; i < 4; i++)
      #pragma unroll
      for (int j = 0; j < 8; j++) acc[i][j] = 0.f;

    for (int k0 = 0; k0 < EMBD; k0 += 16){
      float4 va = *(const float4*)(ea + k0);
      float4 vb = *(const float4*)(wb + k0);
      As[kq+0][lr] = va.x; As[kq+1][lr] = va.y; As[kq+2][lr] = va.z; As[kq+3][lr] = va.w;
      Bs[kq+0][lr] = vb.x; Bs[kq+1][lr] = vb.y; Bs[kq+2][lr] = vb.z; Bs[kq+3][lr] = vb.w;
      __syncthreads();
      #pragma unroll
      for (int k = 0; k < 16; k++){
        float a[4], b[8];
        *(float4*)&a[0] = *(const float4*)&As[k][ty*4];
        #pragma unroll
        for (int j = 0; j < 8; j++) b[j] = Bs[k][tx + 16*j];
        #pragma unroll
        for (int i = 0; i < 4; i++)
          #pragma unroll
          for (int j = 0; j < 8; j++)
            acc[i][j] = fmaf(a[i], b[j], acc[i][j]);
      }
      __syncthreads();
    }
    float bj[8];
    #pragma unroll
    for (int j = 0; j < 8; j++) bj[j] = bias[n0 + tx + 16*j];
    float* Abase = A + (size_t)dir * TSEQ * NGATE;
    #pragma unroll
    for (int i = 0; i < 4; i++){
      float* dst = Abase + (size_t)(t0 + ty*4 + i) * NGATE + n0 + tx;
      #pragma unroll
      for (int j = 0; j < 8; j++) dst[16*j] = acc[i][j] + bj[j];
    }
    __syncthreads();   // drains every wave's stores (HIP barrier semantics)
    if (tid == 0)
      __hip_atomic_fetch_add(&rdy[dir*32 + t_tile], 1,
                             __ATOMIC_RELEASE, __HIP_MEMORY_SCOPE_AGENT);
    return;
  }

  // ================= persistent lstm role =================
  float* hlbuf = (float*)smem;                 // [2][8*68]
  const int bid  = blockIdx.x;
  const int dir  = bid >> 5;
  const int wg   = bid & 31;
  const int lane = tid & 63;
  const int wv   = tid >> 6;        // wave 0..7 = slice index
  const int ul   = tid >> 5;        // unit local 0..15
  const int g    = (tid >> 3) & 3;  // gate i,f,g,o
  const int q    = tid & 7;         // column octant
  const int unit = wg*16 + ul;
  const float* __restrict__ Wh = dir ? Whb : Whf;

  float wreg[64];                   // Wh[g*512+unit][q*64 .. q*64+63]
  {
    const float* wr = Wh + (size_t)(g*HH + unit)*HH + q*64;
    #pragma unroll
    for (int j4 = 0; j4 < 16; j4++){
      float4 vv;
      // volatile load: result cannot be rematerialized -> stays in VGPRs
      asm volatile("global_load_dwordx4 %0, %1, off\n\t"
                   "s_waitcnt vmcnt(0)"
                   : "=v"(vv) : "v"(wr + 4*j4) : "memory");
      wreg[4*j4+0]=vv.x; wreg[4*j4+1]=vv.y; wreg[4*j4+2]=vv.z; wreg[4*j4+3]=vv.w;
    }
  }
  float creg = 0.f;
  if (g == 0 && q == 0) creg = c0[dir*HH + unit];

  u64* mb = hx2 + (size_t)dir*2*HH;
  const float* __restrict__ Ab = A + (size_t)dir*TSEQ*NGATE;
  const int sidx = (wv << 6) + lane;            // this wave's pair index

  // tile-gate + A prefetch for s=0
  int cur_tile = (dir ? (TSEQ - 1) : 0) >> 7;
  {
    const int* rf = rdy + dir*32 + cur_tile;
    while (__hip_atomic_load(rf, __ATOMIC_ACQUIRE, __HIP_MEMORY_SCOPE_AGENT) < 16)
      __builtin_amdgcn_s_sleep(2);
  }
  float av = 0.f;
  if (q == 0) av = Ab[(size_t)(dir ? (TSEQ - 1) : 0)*NGATE + g*HH + unit];

  for (int s = 0; s < TSEQ; s++){
    const int t = dir ? (TSEQ - 1 - s) : s;

    {  // every wave: poll own 64-pair slice (1 load/lane/round, masked reload)
      u64* src = mb + (size_t)(s & 1)*HH;
      const u32 su = (u32)s;
      u64 v = __hip_atomic_load(&src[sidx], __ATOMIC_RELAXED, __HIP_MEMORY_SCOPE_AGENT);
      while (!__all((u32)(v >> 32) == su)){
        if ((u32)(v >> 32) != su)
          v = __hip_atomic_load(&src[sidx], __ATOMIC_RELAXED, __HIP_MEMORY_SCOPE_AGENT);
      }
      hlbuf[(s & 1)*(8*68) + wv*68 + lane] = __uint_as_float((u32)v);
    }
    __syncthreads();

    // prefetch A for step s+1 (resolves under the matvec, off the poll path)
    float av_next = 0.f;
    if (s + 1 < TSEQ){
      const int t1 = dir ? (TSEQ - 2 - s) : (s + 1);
      const int tile1 = t1 >> 7;
      if (tile1 != cur_tile){
        cur_tile = tile1;
        const int* rf = rdy + dir*32 + tile1;
        while (__hip_atomic_load(rf, __ATOMIC_ACQUIRE, __HIP_MEMORY_SCOPE_AGENT) < 16)
          __builtin_amdgcn_s_sleep(2);
      }
      if (q == 0) av_next = Ab[(size_t)t1*NGATE + g*HH + unit];
    }

    // matvec: 64 FMAs from LDS chunk q (weights register-resident)
    const float* hq = hlbuf + (s & 1)*(8*68) + q*68;
    float p0 = 0.f, p1 = 0.f, p2 = 0.f, p3 = 0.f;
    #pragma unroll
    for (int j4 = 0; j4 < 16; j4++){
      float4 h4 = *(const float4*)(hq + 4*j4);
      p0 = fmaf(wreg[4*j4+0], h4.x, p0);
      p1 = fmaf(wreg[4*j4+1], h4.y, p1);
      p2 = fmaf(wreg[4*j4+2], h4.z, p2);
      p3 = fmaf(wreg[4*j4+3], h4.w, p3);
    }
    float acc = ((p0 + p1) + (p2 + p3)) + av;
    acc += __shfl_xor(acc, 1);
    acc += __shfl_xor(acc, 2);
    acc += __shfl_xor(acc, 4);
    // parallel nonlinearity: one transcendental per gate lane
    const float act = (g == 2) ? tanhf(acc) : sigm(acc);
    const float f_ = __shfl_down(act, 8);
    const float g_ = __shfl_down(act, 16);
    const float o_ = __shfl_down(act, 24);
    if (g == 0 && q == 0){
      const float c2 = f_*creg + act*g_;
      const float h2 = o_*tanhf(c2);
      creg = c2;
      // publish FIRST (critical path), bookkeeping store after
      __hip_atomic_store(&mb[(size_t)((s + 1) & 1)*HH + unit], pack_pair(h2, (u32)(s + 1)),
                         __ATOMIC_RELAXED, __HIP_MEMORY_SCOPE_AGENT);
      hseq[((size_t)dir*TSEQ + t)*HH + unit] = h2;
    }
    av = av_next;
  }

  // ---------- feats epilogue: wait for all 64 lstm blocks, then 64 t-rows ------
  __syncthreads();   // all this block's hseq stores issued
  if (tid == 0)
    __hip_atomic_fetch_add(&rdy[65], 1, __ATOMIC_RELEASE, __HIP_MEMORY_SCOPE_AGENT);
  while (__hip_atomic_load(&rdy[65], __ATOMIC_ACQUIRE, __HIP_MEMORY_SCOPE_AGENT) < LSTM_WGS)
    __builtin_amdgcn_s_sleep(2);
  {
    const int wvi = tid >> 6;    // wave 0..7, each does 8 t values
    #pragma unroll
    for (int k = 0; k < 8; k++){
      const int t = bid*64 + wvi*8 + k;
      const float* hf = hseq + (size_t)t*HH;
      const float* hb = hseq + (size_t)(TSEQ + t)*HH;
      float x[16];
      #pragma unroll
      for (int j = 0; j < 8; j++) x[j]     = hf[lane + 64*j];
      #pragma unroll
      for (int j = 0; j < 8; j++) x[8 + j] = hb[lane + 64*j];
      #pragma unroll
      for (int n = 0; n < NTAGS; n++){
        const float* wr = Wout + (size_t)n*(2*HH);
        float p = 0.f;
        #pragma unroll
        for (int j = 0; j < 8; j++) p = fmaf(x[j],     wr[lane + 64*j],      p);
        #pragma unroll
        for (int j = 0; j < 8; j++) p = fmaf(x[8 + j], wr[HH + lane + 64*j], p);
        #pragma unroll
        for (int d = 1; d < 64; d <<= 1) p += __shfl_xor(p, d);
        if (lane == 0) feats[t*8 + n] = p + bout[n];
      }
    }
  }
}

// ---------------- Viterbi forward + backtrack: scalar-in-lane (validated) -------
__global__ __launch_bounds__(64) void k_viterbi(
    const float* __restrict__ trans, const float* __restrict__ feats,
    int* __restrict__ bpw, float* __restrict__ out){
  const int lane = threadIdx.x;
  float T[5][5];
  #pragma unroll
  for (int a = 0; a < 5; a++)
    #pragma unroll
    for (int b = 0; b < 5; b++) T[a][b] = trans[a*NTAGS + b];
  float fv0 = NEGV, fv1 = NEGV, fv2 = NEGV, fv3 = 0.f, fv4 = NEGV; // START=3

  for (int t0 = 0; t0 < TSEQ; t0 += 16){
    float4 fA[16]; float fE[16];
    #pragma unroll
    for (int i = 0; i < 16; i++){
      fA[i] = *(const float4*)(feats + (t0 + i)*8);
      fE[i] = feats[(t0 + i)*8 + 4];
    }
    #pragma unroll
    for (int i = 0; i < 16; i++){
      float nf[5]; int pack = 0;
      #pragma unroll
      for (int to = 0; to < 5; to++){
        const float n0 = fv0 + T[to][0];
        const float n1 = fv1 + T[to][1];
        const float n2 = fv2 + T[to][2];
        const float n3 = fv3 + T[to][3];
        const float n4 = fv4 + T[to][4];
        const float m  = fmaxf(fmaxf(fmaxf(n0, n1), fmaxf(n2, n3)), n4);
        const int idx  = (n0 == m) ? 0 : ((n1 == m) ? 1 : ((n2 == m) ? 2 : ((n3 == m) ? 3 : 4)));
        const float ft = (to == 0) ? fA[i].x : (to == 1) ? fA[i].y :
                         (to == 2) ? fA[i].z : (to == 3) ? fA[i].w : fE[i];
        nf[to] = m + ft;
        pack |= idx << (4*to);
      }
      fv0 = nf[0]; fv1 = nf[1]; fv2 = nf[2]; fv3 = nf[3]; fv4 = nf[4];
      if (lane == 0) bpw[t0 + i] = pack;
    }
  }
  {
    const float n0 = fv0 + T[STOP_TAG][0];
    const float n1 = fv1 + T[STOP_TAG][1];
    const float n2 = fv2 + T[STOP_TAG][2];
    const float n3 = fv3 + T[STOP_TAG][3];
    const float n4 = fv4 + T[STOP_TAG][4];
    const float m  = fmaxf(fmaxf(fmaxf(n0, n1), fmaxf(n2, n3)), n4);
    const int btag = (n0 == m) ? 0 : ((n1 == m) ? 1 : ((n2 == m) ? 2 : ((n3 == m) ? 3 : 4)));
    if (lane == 0){ out[0] = m; out[TSEQ] = (float)btag; }
    int tag = btag;
    for (int tb = TSEQ - 1; tb >= 1; tb -= 16){
      int w[16];
      #pragma unroll
      for (int i = 0; i < 16; i++){
        const int t = tb - i;
        w[i] = (t >= 1) ? bpw[t] : 0;
      }
      #pragma unroll
      for (int i = 0; i < 16; i++){
        const int t = tb - i;
        if (t >= 1){
          const int prev = (w[i] >> (tag*4)) & 15;
          if (lane == 0) out[t] = (float)prev;
          tag = prev;
        }
      }
    }
  }
}

extern "C" void kernel_launch(void* const* d_in, const int* in_sizes, int n_in,
                              void* d_out, int out_size, void* d_ws, size_t ws_size,
                              hipStream_t stream) {
  const int*   sent = (const int*)  d_in[0];
  const float* emb  = (const float*)d_in[1];
  const float* Wihf = (const float*)d_in[2];
  const float* Whhf = (const float*)d_in[3];
  const float* bf_  = (const float*)d_in[4];
  const float* Wihb = (const float*)d_in[5];
  const float* Whhb = (const float*)d_in[6];
  const float* bb_  = (const float*)d_in[7];
  const float* Wout = (const float*)d_in[8];
  const float* bout = (const float*)d_in[9];
  const float* trans= (const float*)d_in[10];
  const float* h0   = (const float*)d_in[11];
  const float* c0   = (const float*)d_in[12];
  float* out = (float*)d_out;

  float* ws   = (float*)d_ws;
  float* A    = ws;                                  // [2][T][2048]
  float* hseq = A    + (size_t)2*TSEQ*NGATE;         // [2][T][512]
  u64*   hx2  = (u64*)(hseq + (size_t)2*TSEQ*HH);    // [2][2][512] (tag,val) pairs
  float* fe   = (float*)(hx2 + 2048);                // [T][8]
  int*   bpw  = (int*)(fe + (size_t)TSEQ*8);         // [T] packed nibbles
  int*   rdy  = bpw + TSEQ;                          // [64] tile-ready + [65] done
  (void)ws_size;

  k_init<<<1, 1024, 0, stream>>>(h0, hx2, rdy);
  k_fused<<<LSTM_WGS + PROJ_WGS, 512, 0, stream>>>(
      sent, emb, Wihf, bf_, Wihb, bb_, Whhf, Whhb, c0, Wout, bout,
      A, hseq, fe, hx2, rdy);
  k_viterbi<<<1, 64, 0, stream>>>(trans, fe, bpw, out);
}

// Round 14
// 8335.509 us; speedup vs baseline: 215.9033x; 1.0741x over previous
//
#include <hip/hip_runtime.h>
#include <hip/hip_bf16.h>
#include <math.h>

#define TSEQ 4096
#define EMBD 1024
#define HH   512
#define NTAGS 5
#define NGATE 2048
#define NEGV (-10000.0f)
#define START_TAG 3
#define STOP_TAG 4
#define LSTM_WGS 64
#define PROJ_WGS 1024
#define VIT_BLOCK (LSTM_WGS + PROJ_WGS)

typedef unsigned long long u64;
typedef unsigned int u32;

__device__ __forceinline__ float sigm(float x){ return 1.0f/(1.0f+expf(-x)); }

__device__ __forceinline__ u64 pack_pair(float h, u32 tag){
  return ((u64)tag << 32) | (u64)__float_as_uint(h);
}

// ---------------- init: prime h pair buffers + zero control counters ----------
__global__ void k_init(const float* __restrict__ h0, u64* __restrict__ hx2,
                       int* __restrict__ rdy){
  int tid = threadIdx.x;
  if (tid < 1024){
    int dir = tid >> 9, u = tid & 511;
    hx2[(dir*2 + 0)*HH + u] = pack_pair(h0[dir*HH + u], 0u);
    hx2[(dir*2 + 1)*HH + u] = pack_pair(0.f, 0xFFFFFFFFu);
  }
  if (tid < 96) rdy[tid] = 0;  // [0..63] tile-ready, [65] lstm-done, [66] feats-done
}

// ------- fully fused: BiLSTM + inproj GEMM + feats epilogue + viterbi ----------
// blocks 0..63: lstm (+feats epilogue). 64..1087: inproj GEMM. 1088: viterbi
// (waits on feats-done counter == 64, then scalar-in-lane forward+backtrack).
__global__ __launch_bounds__(512, 2) void k_fused(
    const int* __restrict__ sent, const float* __restrict__ emb,
    const float* __restrict__ Wif, const float* __restrict__ bf,
    const float* __restrict__ Wib, const float* __restrict__ bb,
    const float* __restrict__ Whf, const float* __restrict__ Whb,
    const float* __restrict__ c0, const float* __restrict__ Wout,
    const float* __restrict__ bout, const float* __restrict__ trans,
    float* __restrict__ A, float* __restrict__ hseq, float* __restrict__ feats,
    int* __restrict__ bpw, float* __restrict__ out,
    u64* __restrict__ hx2, int* __restrict__ rdy){
  __shared__ __align__(16) char smem[17408];
  const int tid = threadIdx.x;

  if (blockIdx.x == VIT_BLOCK){
    // ================= viterbi role (1 wave) =================
    if (tid >= 64) return;
    const int lane = tid;
    while (__hip_atomic_load(&rdy[66], __ATOMIC_ACQUIRE, __HIP_MEMORY_SCOPE_AGENT) < LSTM_WGS)
      __builtin_amdgcn_s_sleep(8);
    float T[5][5];
    #pragma unroll
    for (int a = 0; a < 5; a++)
      #pragma unroll
      for (int b = 0; b < 5; b++) T[a][b] = trans[a*NTAGS + b];
    float fv0 = NEGV, fv1 = NEGV, fv2 = NEGV, fv3 = 0.f, fv4 = NEGV; // START=3

    for (int t0 = 0; t0 < TSEQ; t0 += 16){
      float4 fA[16]; float fE[16];
      #pragma unroll
      for (int i = 0; i < 16; i++){
        fA[i] = *(const float4*)(feats + (t0 + i)*8);
        fE[i] = feats[(t0 + i)*8 + 4];
      }
      #pragma unroll
      for (int i = 0; i < 16; i++){
        float nf[5]; int pack = 0;
        #pragma unroll
        for (int to = 0; to < 5; to++){
          const float n0 = fv0 + T[to][0];
          const float n1 = fv1 + T[to][1];
          const float n2 = fv2 + T[to][2];
          const float n3 = fv3 + T[to][3];
          const float n4 = fv4 + T[to][4];
          const float m  = fmaxf(fmaxf(fmaxf(n0, n1), fmaxf(n2, n3)), n4);
          const int idx  = (n0 == m) ? 0 : ((n1 == m) ? 1 : ((n2 == m) ? 2 : ((n3 == m) ? 3 : 4)));
          const float ft = (to == 0) ? fA[i].x : (to == 1) ? fA[i].y :
                           (to == 2) ? fA[i].z : (to == 3) ? fA[i].w : fE[i];
          nf[to] = m + ft;
          pack |= idx << (4*to);
        }
        fv0 = nf[0]; fv1 = nf[1]; fv2 = nf[2]; fv3 = nf[3]; fv4 = nf[4];
        if (lane == 0) bpw[t0 + i] = pack;
      }
    }
    {
      const float n0 = fv0 + T[STOP_TAG][0];
      const float n1 = fv1 + T[STOP_TAG][1];
      const float n2 = fv2 + T[STOP_TAG][2];
      const float n3 = fv3 + T[STOP_TAG][3];
      const float n4 = fv4 + T[STOP_TAG][4];
      const float m  = fmaxf(fmaxf(fmaxf(n0, n1), fmaxf(n2, n3)), n4);
      const int btag = (n0 == m) ? 0 : ((n1 == m) ? 1 : ((n2 == m) ? 2 : ((n3 == m) ? 3 : 4)));
      if (lane == 0){ out[0] = m; out[TSEQ] = (float)btag; }
      int tag = btag;
      for (int tb = TSEQ - 1; tb >= 1; tb -= 16){
        int w[16];
        #pragma unroll
        for (int i = 0; i < 16; i++){
          const int t = tb - i;
          w[i] = (t >= 1) ? bpw[t] : 0;
        }
        #pragma unroll
        for (int i = 0; i < 16; i++){
          const int t = tb - i;
          if (t >= 1){
            const int prev = (w[i] >> (tag*4)) & 15;
            if (lane == 0) out[t] = (float)prev;
            tag = prev;
          }
        }
      }
    }
    return;
  }

  if (blockIdx.x >= LSTM_WGS){
    // ================= inproj GEMM role =================
    float (*As)[132] = (float(*)[132])smem;              // 16 x 132
    float (*Bs)[132] = (float(*)[132])(smem + 8448);     // 16 x 132
    int* srow        = (int*)(smem + 16896);             // 128
    const int p   = blockIdx.x - LSTM_WGS;               // 0..1023
    const int ti  = p >> 5;                              // 0..31
    const int yy  = p & 31;                              // 0..31
    const int dir = yy >> 4;
    const int t_tile = dir ? (31 - ti) : ti;             // two-ended production
    const int t0  = t_tile * 128;
    const int n0  = (yy & 15) * 128;
    const float* __restrict__ W    = dir ? Wib : Wif;
    const float* __restrict__ bias = dir ? bb : bf;
    if (tid < 128) srow[tid] = sent[t0 + tid];
    __syncthreads();
    const int lr = tid >> 2;            // 0..127
    const int kq = (tid & 3) * 4;
    const float* ea = emb + (size_t)srow[lr]   * EMBD + kq;
    const float* wb = W + (size_t)(n0 + lr)    * EMBD + kq;
    const int tx = tid & 15, ty = tid >> 4;   // ty 0..31
    float acc[4][8];
    #pragma unroll
    for (int i = 0; i < 4; i++)
      #pragma unroll
      for (int j = 0; j < 8; j++) acc[i][j] = 0.f;

    for (int k0 = 0; k0 < EMBD; k0 += 16){
      float4 va = *(const float4*)(ea + k0);
      float4 vb = *(const float4*)(wb + k0);
      As[kq+0][lr] = va.x; As[kq+1][lr] = va.y; As[kq+2][lr] = va.z; As[kq+3][lr] = va.w;
      Bs[kq+0][lr] = vb.x; Bs[kq+1][lr] = vb.y; Bs[kq+2][lr] = vb.z; Bs[kq+3][lr] = vb.w;
      __syncthreads();
      #pragma unroll
      for (int k = 0; k < 16; k++){
        float a[4], b[8];
        *(float4*)&a[0] = *(const float4*)&As[k][ty*4];
        #pragma unroll
        for (int j = 0; j < 8; j++) b[j] = Bs[k][tx + 16*j];
        #pragma unroll
        for (int i = 0; i < 4; i++)
          #pragma unroll
          for (int j = 0; j < 8; j++)
            acc[i][j] = fmaf(a[i], b[j], acc[i][j]);
      }
      __syncthreads();
    }
    float bj[8];
    #pragma unroll
    for (int j = 0; j < 8; j++) bj[j] = bias[n0 + tx + 16*j];
    float* Abase = A + (size_t)dir * TSEQ * NGATE;
    #pragma unroll
    for (int i = 0; i < 4; i++){
      float* dst = Abase + (size_t)(t0 + ty*4 + i) * NGATE + n0 + tx;
      #pragma unroll
      for (int j = 0; j < 8; j++) dst[16*j] = acc[i][j] + bj[j];
    }
    __syncthreads();   // drains every wave's stores (HIP barrier semantics)
    if (tid == 0)
      __hip_atomic_fetch_add(&rdy[dir*32 + t_tile], 1,
                             __ATOMIC_RELEASE, __HIP_MEMORY_SCOPE_AGENT);
    return;
  }

  // ================= persistent lstm role =================
  float* hlbuf = (float*)smem;                 // [2][8*68]
  const int bid  = blockIdx.x;
  const int dir  = bid >> 5;
  const int wg   = bid & 31;
  const int lane = tid & 63;
  const int wv   = tid >> 6;        // wave 0..7 = slice index
  const int ul   = tid >> 5;        // unit local 0..15
  const int g    = (tid >> 3) & 3;  // gate i,f,g,o
  const int q    = tid & 7;         // column octant
  const int unit = wg*16 + ul;
  const float* __restrict__ Wh = dir ? Whb : Whf;

  float wreg[64];                   // Wh[g*512+unit][q*64 .. q*64+63]
  {
    const float* wr = Wh + (size_t)(g*HH + unit)*HH + q*64;
    #pragma unroll
    for (int j4 = 0; j4 < 16; j4++){
      float4 vv;
      // volatile load: result cannot be rematerialized -> stays in VGPRs
      asm volatile("global_load_dwordx4 %0, %1, off\n\t"
                   "s_waitcnt vmcnt(0)"
                   : "=v"(vv) : "v"(wr + 4*j4) : "memory");
      wreg[4*j4+0]=vv.x; wreg[4*j4+1]=vv.y; wreg[4*j4+2]=vv.z; wreg[4*j4+3]=vv.w;
    }
  }
  float creg = 0.f;
  if (g == 0 && q == 0) creg = c0[dir*HH + unit];

  u64* mb = hx2 + (size_t)dir*2*HH;
  const float* __restrict__ Ab = A + (size_t)dir*TSEQ*NGATE;
  const int sidx = (wv << 6) + lane;            // this wave's pair index

  // tile-gate + A prefetch for s=0
  int cur_tile = (dir ? (TSEQ - 1) : 0) >> 7;
  {
    const int* rf = rdy + dir*32 + cur_tile;
    while (__hip_atomic_load(rf, __ATOMIC_ACQUIRE, __HIP_MEMORY_SCOPE_AGENT) < 16)
      __builtin_amdgcn_s_sleep(2);
  }
  float av = 0.f;
  if (q == 0) av = Ab[(size_t)(dir ? (TSEQ - 1) : 0)*NGATE + g*HH + unit];

  for (int s = 0; s < TSEQ; s++){
    const int t = dir ? (TSEQ - 1 - s) : s;

    {  // every wave: poll own 64-pair slice (1 load/lane/round, masked reload)
      u64* src = mb + (size_t)(s & 1)*HH;
      const u32 su = (u32)s;
      u64 v = __hip_atomic_load(&src[sidx], __ATOMIC_RELAXED, __HIP_MEMORY_SCOPE_AGENT);
      while (!__all((u32)(v >> 32) == su)){
        if ((u32)(v >> 32) != su)
          v = __hip_atomic_load(&src[sidx], __ATOMIC_RELAXED, __HIP_MEMORY_SCOPE_AGENT);
      }
      hlbuf[(s & 1)*(8*68) + wv*68 + lane] = __uint_as_float((u32)v);
    }
    __syncthreads();

    // prefetch A for step s+1 (resolves under the matvec, off the poll path)
    float av_next = 0.f;
    if (s + 1 < TSEQ){
      const int t1 = dir ? (TSEQ - 2 - s) : (s + 1);
      const int tile1 = t1 >> 7;
      if (tile1 != cur_tile){
        cur_tile = tile1;
        const int* rf = rdy + dir*32 + tile1;
        while (__hip_atomic_load(rf, __ATOMIC_ACQUIRE, __HIP_MEMORY_SCOPE_AGENT) < 16)
          __builtin_amdgcn_s_sleep(2);
      }
      if (q == 0) av_next = Ab[(size_t)t1*NGATE + g*HH + unit];
    }

    // matvec: 64 FMAs from LDS chunk q (weights register-resident)
    const float* hq = hlbuf + (s & 1)*(8*68) + q*68;
    float p0 = 0.f, p1 = 0.f, p2 = 0.f, p3 = 0.f;
    #pragma unroll
    for (int j4 = 0; j4 < 16; j4++){
      float4 h4 = *(const float4*)(hq + 4*j4);
      p0 = fmaf(wreg[4*j4+0], h4.x, p0);
      p1 = fmaf(wreg[4*j4+1], h4.y, p1);
      p2 = fmaf(wreg[4*j4+2], h4.z, p2);
      p3 = fmaf(wreg[4*j4+3], h4.w, p3);
    }
    float acc = ((p0 + p1) + (p2 + p3)) + av;
    acc += __shfl_xor(acc, 1);
    acc += __shfl_xor(acc, 2);
    acc += __shfl_xor(acc, 4);
    // parallel nonlinearity: one transcendental per gate lane
    const float act = (g == 2) ? tanhf(acc) : sigm(acc);
    const float f_ = __shfl_down(act, 8);
    const float g_ = __shfl_down(act, 16);
    const float o_ = __shfl_down(act, 24);
    if (g == 0 && q == 0){
      const float c2 = f_*creg + act*g_;
      const float h2 = o_*tanhf(c2);
      creg = c2;
      // publish FIRST (critical path), bookkeeping store after
      __hip_atomic_store(&mb[(size_t)((s + 1) & 1)*HH + unit], pack_pair(h2, (u32)(s + 1)),
                         __ATOMIC_RELAXED, __HIP_MEMORY_SCOPE_AGENT);
      hseq[((size_t)dir*TSEQ + t)*HH + unit] = h2;
    }
    av = av_next;
  }

  // ---------- feats epilogue: wait for all 64 lstm blocks, then 64 t-rows ------
  __syncthreads();   // all this block's hseq stores issued
  if (tid == 0)
    __hip_atomic_fetch_add(&rdy[65], 1, __ATOMIC_RELEASE, __HIP_MEMORY_SCOPE_AGENT);
  while (__hip_atomic_load(&rdy[65], __ATOMIC_ACQUIRE, __HIP_MEMORY_SCOPE_AGENT) < LSTM_WGS)
    __builtin_amdgcn_s_sleep(2);
  {
    const int wvi = tid >> 6;    // wave 0..7, each does 8 t values
    #pragma unroll
    for (int k = 0; k < 8; k++){
      const int t = bid*64 + wvi*8 + k;
      const float* hf = hseq + (size_t)t*HH;
      const float* hb = hseq + (size_t)(TSEQ + t)*HH;
      float x[16];
      #pragma unroll
      for (int j = 0; j < 8; j++) x[j]     = hf[lane + 64*j];
      #pragma unroll
      for (int j = 0; j < 8; j++) x[8 + j] = hb[lane + 64*j];
      #pragma unroll
      for (int n = 0; n < NTAGS; n++){
        const float* wr = Wout + (size_t)n*(2*HH);
        float p = 0.f;
        #pragma unroll
        for (int j = 0; j < 8; j++) p = fmaf(x[j],     wr[lane + 64*j],      p);
        #pragma unroll
        for (int j = 0; j < 8; j++) p = fmaf(x[8 + j], wr[HH + lane + 64*j], p);
        #pragma unroll
        for (int d = 1; d < 64; d <<= 1) p += __shfl_xor(p, d);
        if (lane == 0) feats[t*8 + n] = p + bout[n];
      }
    }
  }
  __syncthreads();   // all this block's feats stores issued
  if (tid == 0)
    __hip_atomic_fetch_add(&rdy[66], 1, __ATOMIC_RELEASE, __HIP_MEMORY_SCOPE_AGENT);
}

extern "C" void kernel_launch(void* const* d_in, const int* in_sizes, int n_in,
                              void* d_out, int out_size, void* d_ws, size_t ws_size,
                              hipStream_t stream) {
  const int*   sent = (const int*)  d_in[0];
  const float* emb  = (const float*)d_in[1];
  const float* Wihf = (const float*)d_in[2];
  const float* Whhf = (const float*)d_in[3];
  const float* bf_  = (const float*)d_in[4];
  const float* Wihb = (const float*)d_in[5];
  const float* Whhb = (const float*)d_in[6];
  const float* bb_  = (const float*)d_in[7];
  const float* Wout = (const float*)d_in[8];
  const float* bout = (const float*)d_in[9];
  const float* trans= (const float*)d_in[10];
  const float* h0   = (const float*)d_in[11];
  const float* c0   = (const float*)d_in[12];
  float* out = (float*)d_out;

  float* ws   = (float*)d_ws;
  float* A    = ws;                                  // [2][T][2048]
  float* hseq = A    + (size_t)2*TSEQ*NGATE;         // [2][T][512]
  u64*   hx2  = (u64*)(hseq + (size_t)2*TSEQ*HH);    // [2][2][512] (tag,val) pairs
  float* fe   = (float*)(hx2 + 2048);                // [T][8]
  int*   bpw  = (int*)(fe + (size_t)TSEQ*8);         // [T] packed nibbles
  int*   rdy  = bpw + TSEQ;                          // [64] tile-ready + [65][66]
  (void)ws_size;

  k_init<<<1, 1024, 0, stream>>>(h0, hx2, rdy);
  k_fused<<<VIT_BLOCK + 1, 512, 0, stream>>>(
      sent, emb, Wihf, bf_, Wihb, bb_, Whhf, Whhb, c0, Wout, bout, trans,
      A, hseq, fe, bpw, out, hx2, rdy);
}